// Round 1
// baseline (1594.689 us; speedup 1.0000x reference)
//
#include <hip/hip_runtime.h>
#include <math.h>

#define NN 50000
#define EE 800000
#define DD 128
#define HH 4
#define CC 32
#define LL 2

// ---------------- edge sorting (by dst) ----------------

__global__ __launch_bounds__(256) void k_hist(const int* __restrict__ dstA, int* __restrict__ deg){
    int e = blockIdx.x * 256 + threadIdx.x;
    if (e < EE) atomicAdd(&deg[dstA[e]], 1);
}

__global__ __launch_bounds__(1024) void k_scan(const int* __restrict__ deg, int* __restrict__ offs){
    __shared__ int buf[1024];
    int t = threadIdx.x;
    int base = 0;
    if (t == 0) offs[0] = 0;
    for (int c0 = 0; c0 < NN; c0 += 1024){
        int i = c0 + t;
        int v = (i < NN) ? deg[i] : 0;
        buf[t] = v;
        __syncthreads();
        for (int off = 1; off < 1024; off <<= 1){
            int x = (t >= off) ? buf[t - off] : 0;
            __syncthreads();
            buf[t] += x;
            __syncthreads();
        }
        if (i < NN) offs[i + 1] = base + buf[t];
        base += buf[1023];
        __syncthreads();
    }
}

__global__ __launch_bounds__(256) void k_scatter(const int* __restrict__ srcA, const int* __restrict__ dstA,
                                                 const int* __restrict__ offs, int* __restrict__ cnt,
                                                 int* __restrict__ perm, int* __restrict__ srcs){
    int e = blockIdx.x * 256 + threadIdx.x;
    if (e < EE){
        int d = dstA[e];
        int pos = offs[d] + atomicAdd(&cnt[d], 1);
        perm[pos] = e;
        srcs[pos] = srcA[e];
    }
}

// loop_attr[n,c] = mean over incoming edges of ea[e,c] (0 if deg==0)
__global__ __launch_bounds__(256) void k_loopattr(const float* __restrict__ ea, const int* __restrict__ perm,
                                                  const int* __restrict__ offs, float* __restrict__ la){
    int tid = blockIdx.x * 256 + threadIdx.x;
    if (tid >= NN * CC) return;
    int n = tid >> 5, c = tid & 31;
    int b = offs[n], e = offs[n + 1];
    float s = 0.f;
    for (int p = b; p < e; ++p) s += ea[perm[p] * CC + c];
    la[tid] = s / fmaxf((float)(e - b), 1.0f);
}

// ---------------- fp32 GEMM: Y[r,c] = act( sum_k X[r,k]*W[k,c] + bv[c] ) ----------------
// BM=64 rows/block, full N=128 cols, BK=32. 256 threads: (ty,tx) 16x16, each 4 rows x 8 cols.

__global__ __launch_bounds__(256) void k_gemm(const float* __restrict__ X, const float* __restrict__ W,
                                              const float* __restrict__ bv, float* __restrict__ Y, int act){
    __shared__ float Xs[64][33];
    __shared__ float Ws[32][128];
    int tid = threadIdx.x;
    int tx = tid & 15, ty = tid >> 4;
    int r0 = blockIdx.x * 64;
    float acc[4][8];
    #pragma unroll
    for (int i = 0; i < 4; i++)
        #pragma unroll
        for (int j = 0; j < 8; j++) acc[i][j] = 0.f;

    for (int k0 = 0; k0 < 128; k0 += 32){
        {   // load X tile: 64 rows x 32 k
            int flat = tid * 8;
            int row = flat >> 5;
            int kk = flat & 31;
            int gr = r0 + row; if (gr >= NN) gr = NN - 1;
            const float* s = X + (size_t)gr * 128 + k0 + kk;
            float4 v0 = *(const float4*)s;
            float4 v1 = *(const float4*)(s + 4);
            float* d = &Xs[row][kk];
            d[0]=v0.x; d[1]=v0.y; d[2]=v0.z; d[3]=v0.w;
            d[4]=v1.x; d[5]=v1.y; d[6]=v1.z; d[7]=v1.w;
        }
        {   // load W tile: 32 k x 128 cols
            int flat = tid * 16;
            int kr = flat >> 7, c = flat & 127;
            const float4* s = (const float4*)(W + (size_t)(k0 + kr) * 128 + c);
            float4* d = (float4*)&Ws[kr][c];
            d[0] = s[0]; d[1] = s[1]; d[2] = s[2]; d[3] = s[3];
        }
        __syncthreads();
        #pragma unroll
        for (int kk = 0; kk < 32; kk++){
            float aa[4];
            #pragma unroll
            for (int i = 0; i < 4; i++) aa[i] = Xs[ty * 4 + i][kk];
            float bb[8];
            *(float4*)&bb[0] = *(float4*)&Ws[kk][tx * 8];
            *(float4*)&bb[4] = *(float4*)&Ws[kk][tx * 8 + 4];
            #pragma unroll
            for (int i = 0; i < 4; i++)
                #pragma unroll
                for (int j = 0; j < 8; j++) acc[i][j] = fmaf(aa[i], bb[j], acc[i][j]);
        }
        __syncthreads();
    }
    #pragma unroll
    for (int i = 0; i < 4; i++){
        int r = r0 + ty * 4 + i;
        if (r < NN){
            #pragma unroll
            for (int j = 0; j < 8; j++){
                int c = tx * 8 + j;
                float v = acc[i][j] + bv[c];
                if (act) v = fmaxf(v, 0.f);
                Y[(size_t)r * 128 + c] = v;
            }
        }
    }
}

// ---------------- fused GATv2 edge softmax + aggregation: one wave per node ----------------
// lane owns channels d0=lane (head lane>>5), d1=lane+64 (head 2+(lane>>5)).

__global__ __launch_bounds__(256) void k_gat(const float* __restrict__ xl, const float* __restrict__ xr,
                                             const float* __restrict__ ea, const int* __restrict__ srcs,
                                             const int* __restrict__ perm, const int* __restrict__ offs,
                                             const float* __restrict__ la, const float* __restrict__ We,
                                             const float* __restrict__ att, const float* __restrict__ bias,
                                             float* __restrict__ out){
    int n = blockIdx.x * 4 + (threadIdx.x >> 6);
    int lane = threadIdx.x & 63;
    int cc = lane & 31;

    // We columns for this lane's two channels, in registers (32x2)
    float w0[32], w1r[32];
    #pragma unroll
    for (int k = 0; k < 32; k++){
        w0[k]  = We[k * 128 + lane];
        w1r[k] = We[k * 128 + 64 + lane];
    }
    float att0 = att[lane], att1 = att[64 + lane];
    float xr0 = xr[(size_t)n * 128 + lane], xr1 = xr[(size_t)n * 128 + 64 + lane];
    float b0v = bias[lane], b1v = bias[64 + lane];

    int beg = offs[n], end = offs[n + 1];
    float M0 = -INFINITY, M1 = -INFINITY;
    float S0 = 0.f, S1 = 0.f, A0 = 0.f, A1 = 0.f;

    for (int pos = beg; pos <= end; ++pos){
        int sn; float eav;
        if (pos < end){
            sn = srcs[pos];
            eav = ea[(size_t)perm[pos] * 32 + cc];
        } else {            // self-loop, processed last (max is order-independent)
            sn = n;
            eav = la[(size_t)n * 32 + cc];
        }
        float xl0 = xl[(size_t)sn * 128 + lane];
        float xl1 = xl[(size_t)sn * 128 + 64 + lane];

        // ee[d] = sum_k ea2[e][k] * We[k][d]
        float e0 = 0.f, e1 = 0.f;
        #pragma unroll
        for (int k = 0; k < 32; k++){
            float ev = __shfl(eav, k);
            e0 = fmaf(ev, w0[k], e0);
            e1 = fmaf(ev, w1r[k], e1);
        }
        float m0 = xl0 + xr0 + e0;
        float m1 = xl1 + xr1 + e1;
        m0 = (m0 > 0.f) ? m0 : 0.2f * m0;
        m1 = (m1 > 0.f) ? m1 : 0.2f * m1;
        float p0 = m0 * att0, p1 = m1 * att1;
        // per-head reduction over 32 channels (lanes 0-31 / 32-63 are distinct heads)
        #pragma unroll
        for (int o = 16; o > 0; o >>= 1){
            p0 += __shfl_xor(p0, o);
            p1 += __shfl_xor(p1, o);
        }
        // online softmax update (slot 0)
        float nM = fmaxf(M0, p0);
        float rs = __expf(M0 - nM);
        float wv = __expf(p0 - nM);
        S0 = S0 * rs + wv; A0 = A0 * rs + wv * xl0; M0 = nM;
        // slot 1
        nM = fmaxf(M1, p1);
        rs = __expf(M1 - nM);
        wv = __expf(p1 - nM);
        S1 = S1 * rs + wv; A1 = A1 * rs + wv * xl1; M1 = nM;
    }
    out[(size_t)n * 128 + lane]      = A0 / (S0 + 1e-16f) + b0v;
    out[(size_t)n * 128 + 64 + lane] = A1 / (S1 + 1e-16f) + b1v;
}

// ---------------- driver ----------------

extern "C" void kernel_launch(void* const* d_in, const int* in_sizes, int n_in,
                              void* d_out, int out_size, void* d_ws, size_t ws_size,
                              hipStream_t stream){
    const float* nodes = (const float*)d_in[0];
    const int*   ei    = (const int*)d_in[1];
    const float* ea    = (const float*)d_in[2];
    const float* Wl    = (const float*)d_in[3];
    const float* bl    = (const float*)d_in[4];
    const float* Wr    = (const float*)d_in[5];
    const float* br    = (const float*)d_in[6];
    const float* We    = (const float*)d_in[7];
    const float* att   = (const float*)d_in[8];
    const float* bias  = (const float*)d_in[9];
    const float* w1    = (const float*)d_in[10];
    const float* b1    = (const float*)d_in[11];
    const float* w2    = (const float*)d_in[12];
    const float* b2    = (const float*)d_in[13];
    const int* srcA = ei;
    const int* dstA = ei + EE;

    char* ws = (char*)d_ws;
    size_t off = 0;
    auto alloc = [&](size_t bytes) -> char* {
        off = (off + 255) & ~(size_t)255;
        char* p = ws + off;
        off += bytes;
        return p;
    };
    int*   deg  = (int*)alloc(NN * 4);
    int*   cnt  = (int*)alloc(NN * 4);
    int*   offs = (int*)alloc((NN + 1) * 4);
    int*   perm = (int*)alloc((size_t)EE * 4);
    int*   srcs = (int*)alloc((size_t)EE * 4);
    float* la   = (float*)alloc((size_t)NN * CC * 4);
    float* xl   = (float*)alloc((size_t)NN * DD * 4);
    float* xr   = (float*)alloc((size_t)NN * DD * 4);
    float* bg   = (float*)alloc((size_t)NN * DD * 4);   // GAT layer output
    float* bh   = (float*)alloc((size_t)NN * DD * 4);   // MLP hidden
    float* bx   = (float*)alloc((size_t)NN * DD * 4);   // inter-layer x

    hipMemsetAsync(deg, 0, NN * 4, stream);
    hipMemsetAsync(cnt, 0, NN * 4, stream);
    k_hist<<<(EE + 255) / 256, 256, 0, stream>>>(dstA, deg);
    k_scan<<<1, 1024, 0, stream>>>(deg, offs);
    k_scatter<<<(EE + 255) / 256, 256, 0, stream>>>(srcA, dstA, offs, cnt, perm, srcs);
    k_loopattr<<<(NN * CC + 255) / 256, 256, 0, stream>>>(ea, perm, offs, la);

    const float* x = nodes;
    for (int l = 0; l < LL; l++){
        k_gemm<<<(NN + 63) / 64, 256, 0, stream>>>(x, Wl + l * DD * DD, bl + l * DD, xl, 0);
        k_gemm<<<(NN + 63) / 64, 256, 0, stream>>>(x, Wr + l * DD * DD, br + l * DD, xr, 0);
        k_gat<<<NN / 4, 256, 0, stream>>>(xl, xr, ea, srcs, perm, offs, la,
                                          We + l * CC * DD, att + l * HH * CC, bias + l * DD, bg);
        k_gemm<<<(NN + 63) / 64, 256, 0, stream>>>(bg, w1 + l * DD * DD, b1 + l * DD, bh, 1);
        float* yo = (l == LL - 1) ? (float*)d_out : bx;
        k_gemm<<<(NN + 63) / 64, 256, 0, stream>>>(bh, w2 + l * DD * DD, b2 + l * DD, yo, 0);
        x = bx;
    }
}

// Round 2
// 1233.583 us; speedup vs baseline: 1.2927x; 1.2927x over previous
//
#include <hip/hip_runtime.h>
#include <math.h>

#define NN 50000
#define EE 800000
#define DD 128
#define HH 4
#define CC 32
#define LL 2

// ---------------- edge sorting (by dst) ----------------

__global__ __launch_bounds__(256) void k_hist(const int* __restrict__ dstA, int* __restrict__ deg){
    int e = blockIdx.x * 256 + threadIdx.x;
    if (e < EE) atomicAdd(&deg[dstA[e]], 1);
}

// 3-phase parallel scan: offs[i+1] = inclusive_sum(deg[0..i])
__global__ __launch_bounds__(1024) void k_scan1(const int* __restrict__ deg, int* __restrict__ offs,
                                                int* __restrict__ bsum){
    __shared__ int buf[1024];
    int t = threadIdx.x;
    int i = blockIdx.x * 1024 + t;
    int v = (i < NN) ? deg[i] : 0;
    buf[t] = v;
    __syncthreads();
    for (int off = 1; off < 1024; off <<= 1){
        int x = (t >= off) ? buf[t - off] : 0;
        __syncthreads();
        buf[t] += x;
        __syncthreads();
    }
    if (i < NN) offs[i + 1] = buf[t];
    if (t == 1023) bsum[blockIdx.x] = buf[1023];
    if (i == 0) offs[0] = 0;
}

__global__ void k_scan2(int* __restrict__ bsum, int nb){
    if (threadIdx.x == 0){
        int s = 0;
        for (int b = 0; b < nb; b++){ int v = bsum[b]; bsum[b] = s; s += v; }
    }
}

__global__ __launch_bounds__(1024) void k_scan3(int* __restrict__ offs, const int* __restrict__ bsum){
    int i = blockIdx.x * 1024 + threadIdx.x;
    if (i < NN) offs[i + 1] += bsum[i >> 10];
}

__global__ __launch_bounds__(256) void k_scatter(const int* __restrict__ srcA, const int* __restrict__ dstA,
                                                 const int* __restrict__ offs, int* __restrict__ cnt,
                                                 int* __restrict__ perm, int* __restrict__ srcs){
    int e = blockIdx.x * 256 + threadIdx.x;
    if (e < EE){
        int d = dstA[e];
        int pos = offs[d] + atomicAdd(&cnt[d], 1);
        perm[pos] = e;
        srcs[pos] = srcA[e];
    }
}

// loop_attr[n,c] = mean over incoming edges of ea[e,c] (0 if deg==0)
__global__ __launch_bounds__(256) void k_loopattr(const float* __restrict__ ea, const int* __restrict__ perm,
                                                  const int* __restrict__ offs, float* __restrict__ la){
    int tid = blockIdx.x * 256 + threadIdx.x;
    if (tid >= NN * CC) return;
    int n = tid >> 5, c = tid & 31;
    int b = offs[n], e = offs[n + 1];
    float s = 0.f;
    for (int p = b; p < e; ++p) s += ea[perm[p] * CC + c];
    la[tid] = s / fmaxf((float)(e - b), 1.0f);
}

// ---------------- fp32 GEMM: Y[r,c] = act( sum_k X[r,k]*W[k,c] + bv[c] ) ----------------

__global__ __launch_bounds__(256) void k_gemm(const float* __restrict__ X, const float* __restrict__ W,
                                              const float* __restrict__ bv, float* __restrict__ Y, int act){
    __shared__ float Xs[64][33];
    __shared__ float Ws[32][128];
    int tid = threadIdx.x;
    int tx = tid & 15, ty = tid >> 4;
    int r0 = blockIdx.x * 64;
    float acc[4][8];
    #pragma unroll
    for (int i = 0; i < 4; i++)
        #pragma unroll
        for (int j = 0; j < 8; j++) acc[i][j] = 0.f;

    for (int k0 = 0; k0 < 128; k0 += 32){
        {
            int flat = tid * 8;
            int row = flat >> 5;
            int kk = flat & 31;
            int gr = r0 + row; if (gr >= NN) gr = NN - 1;
            const float* s = X + (size_t)gr * 128 + k0 + kk;
            float4 v0 = *(const float4*)s;
            float4 v1 = *(const float4*)(s + 4);
            float* d = &Xs[row][kk];
            d[0]=v0.x; d[1]=v0.y; d[2]=v0.z; d[3]=v0.w;
            d[4]=v1.x; d[5]=v1.y; d[6]=v1.z; d[7]=v1.w;
        }
        {
            int flat = tid * 16;
            int kr = flat >> 7, c = flat & 127;
            const float4* s = (const float4*)(W + (size_t)(k0 + kr) * 128 + c);
            float4* d = (float4*)&Ws[kr][c];
            d[0] = s[0]; d[1] = s[1]; d[2] = s[2]; d[3] = s[3];
        }
        __syncthreads();
        #pragma unroll
        for (int kk = 0; kk < 32; kk++){
            float aa[4];
            #pragma unroll
            for (int i = 0; i < 4; i++) aa[i] = Xs[ty * 4 + i][kk];
            float bb[8];
            *(float4*)&bb[0] = *(float4*)&Ws[kk][tx * 8];
            *(float4*)&bb[4] = *(float4*)&Ws[kk][tx * 8 + 4];
            #pragma unroll
            for (int i = 0; i < 4; i++)
                #pragma unroll
                for (int j = 0; j < 8; j++) acc[i][j] = fmaf(aa[i], bb[j], acc[i][j]);
        }
        __syncthreads();
    }
    #pragma unroll
    for (int i = 0; i < 4; i++){
        int r = r0 + ty * 4 + i;
        if (r < NN){
            #pragma unroll
            for (int j = 0; j < 8; j++){
                int c = tx * 8 + j;
                float v = acc[i][j] + bv[c];
                if (act) v = fmaxf(v, 0.f);
                Y[(size_t)r * 128 + c] = v;
            }
        }
    }
}

// ---------------- edge projection GEMM: eep[pos] = bf16pack( ea2[pos] @ We ) ----------------
// pos < EE: row ea[perm[pos]]; pos >= EE: row la[pos-EE].
// One wave per 2 positions; lane owns output channels (lane, lane+64), packed into one uint.

__device__ inline unsigned int pack_bf16(float lo, float hi){
    unsigned int a = __float_as_uint(lo), b = __float_as_uint(hi);
    a = (a + 0x7fffu + ((a >> 16) & 1u)) >> 16;
    b = (b + 0x7fffu + ((b >> 16) & 1u)) & 0xffff0000u;
    return a | b;
}

__global__ __launch_bounds__(256) void k_edgegemm(const float* __restrict__ ea, const float* __restrict__ la,
                                                  const int* __restrict__ perm, const float* __restrict__ We,
                                                  unsigned int* __restrict__ eep){
    int wid = (blockIdx.x * 256 + threadIdx.x) >> 6;
    int nw = (gridDim.x * 256) >> 6;
    int lane = threadIdx.x & 63;
    int cc = lane & 31;
    float w0[32], w1[32];
    #pragma unroll
    for (int k = 0; k < 32; k++){
        w0[k] = We[k * 128 + lane];
        w1[k] = We[k * 128 + 64 + lane];
    }
    const int TOT = EE + NN;
    for (int base = wid * 2; base < TOT; base += nw * 2){
        int p0 = base, p1 = base + 1;
        float ev0 = (p0 < EE) ? ea[(size_t)perm[p0] * 32 + cc] : la[(size_t)(p0 - EE) * 32 + cc];
        bool has1 = p1 < TOT;
        float ev1 = 0.f;
        if (has1) ev1 = (p1 < EE) ? ea[(size_t)perm[p1] * 32 + cc] : la[(size_t)(p1 - EE) * 32 + cc];
        float a00 = 0.f, a01 = 0.f, a10 = 0.f, a11 = 0.f;
        #pragma unroll
        for (int k = 0; k < 32; k++){
            float b0 = __int_as_float(__builtin_amdgcn_readlane(__float_as_int(ev0), k));
            float b1 = __int_as_float(__builtin_amdgcn_readlane(__float_as_int(ev1), k));
            a00 = fmaf(b0, w0[k], a00);
            a01 = fmaf(b0, w1[k], a01);
            a10 = fmaf(b1, w0[k], a10);
            a11 = fmaf(b1, w1[k], a11);
        }
        eep[(size_t)p0 * 64 + lane] = pack_bf16(a00, a01);
        if (has1) eep[(size_t)p1 * 64 + lane] = pack_bf16(a10, a11);
    }
}

// ---------------- fused GATv2 softmax + aggregation: one wave per node, 2 edges/iter ----------------

__global__ __launch_bounds__(256) void k_gat(const float* __restrict__ xl, const float* __restrict__ xr,
                                             const int* __restrict__ srcs, const int* __restrict__ offs,
                                             const unsigned int* __restrict__ eep,
                                             const float* __restrict__ att, const float* __restrict__ bias,
                                             float* __restrict__ out){
    int n = blockIdx.x * 4 + (threadIdx.x >> 6);
    int lane = threadIdx.x & 63;

    float att0 = att[lane], att1 = att[64 + lane];
    float xr0 = xr[(size_t)n * 128 + lane], xr1 = xr[(size_t)n * 128 + 64 + lane];

    int beg = offs[n];
    int deg = offs[n + 1] - beg;
    int cnt = deg + 1;   // + self-loop

    float M0 = -INFINITY, M1 = -INFINITY;
    float S0 = 0.f, S1 = 0.f, A0 = 0.f, A1 = 0.f;

    for (int i = 0; i < cnt; i += 2){
        // element a
        int sa = (i < deg) ? srcs[beg + i] : n;
        size_t pa = (i < deg) ? (size_t)(beg + i) : (size_t)(EE + n);
        // element b
        bool hb = (i + 1) < cnt;
        int ib = i + 1;
        int sb = (hb && ib < deg) ? srcs[beg + ib] : n;
        size_t pb = (hb && ib < deg) ? (size_t)(beg + ib) : (size_t)(EE + n);

        unsigned int ua = eep[pa * 64 + lane];
        unsigned int ub = eep[pb * 64 + lane];
        float xla0 = xl[(size_t)sa * 128 + lane], xla1 = xl[(size_t)sa * 128 + 64 + lane];
        float xlb0 = xl[(size_t)sb * 128 + lane], xlb1 = xl[(size_t)sb * 128 + 64 + lane];

        float ea0 = __uint_as_float(ua << 16);
        float ea1 = __uint_as_float(ua & 0xffff0000u);
        float eb0 = __uint_as_float(ub << 16);
        float eb1 = __uint_as_float(ub & 0xffff0000u);

        float ma0 = xla0 + xr0 + ea0;
        float ma1 = xla1 + xr1 + ea1;
        float mb0 = xlb0 + xr0 + eb0;
        float mb1 = xlb1 + xr1 + eb1;
        ma0 = (ma0 > 0.f) ? ma0 : 0.2f * ma0;
        ma1 = (ma1 > 0.f) ? ma1 : 0.2f * ma1;
        mb0 = (mb0 > 0.f) ? mb0 : 0.2f * mb0;
        mb1 = (mb1 > 0.f) ? mb1 : 0.2f * mb1;

        float pa0 = ma0 * att0, pa1 = ma1 * att1;
        float pb0 = mb0 * att0, pb1 = mb1 * att1;
        #pragma unroll
        for (int o = 16; o > 0; o >>= 1){
            pa0 += __shfl_xor(pa0, o);
            pa1 += __shfl_xor(pa1, o);
            pb0 += __shfl_xor(pb0, o);
            pb1 += __shfl_xor(pb1, o);
        }
        if (!hb){ pb0 = -INFINITY; pb1 = -INFINITY; }

        // combined online-softmax update, slot 0 (channels [0,64))
        float nM = fmaxf(M0, fmaxf(pa0, pb0));
        float rs = __expf(M0 - nM);
        float wa = __expf(pa0 - nM);
        float wb = __expf(pb0 - nM);
        S0 = S0 * rs + wa + wb;
        A0 = A0 * rs + wa * xla0 + wb * xlb0;
        M0 = nM;
        // slot 1 (channels [64,128))
        nM = fmaxf(M1, fmaxf(pa1, pb1));
        rs = __expf(M1 - nM);
        wa = __expf(pa1 - nM);
        wb = __expf(pb1 - nM);
        S1 = S1 * rs + wa + wb;
        A1 = A1 * rs + wa * xla1 + wb * xlb1;
        M1 = nM;
    }
    out[(size_t)n * 128 + lane]      = A0 / (S0 + 1e-16f) + bias[lane];
    out[(size_t)n * 128 + 64 + lane] = A1 / (S1 + 1e-16f) + bias[64 + lane];
}

// ---------------- driver ----------------

extern "C" void kernel_launch(void* const* d_in, const int* in_sizes, int n_in,
                              void* d_out, int out_size, void* d_ws, size_t ws_size,
                              hipStream_t stream){
    const int*   ei    = (const int*)d_in[1];
    const float* nodes = (const float*)d_in[0];
    const float* ea    = (const float*)d_in[2];
    const float* Wl    = (const float*)d_in[3];
    const float* bl    = (const float*)d_in[4];
    const float* Wr    = (const float*)d_in[5];
    const float* br    = (const float*)d_in[6];
    const float* We    = (const float*)d_in[7];
    const float* att   = (const float*)d_in[8];
    const float* bias  = (const float*)d_in[9];
    const float* w1    = (const float*)d_in[10];
    const float* b1    = (const float*)d_in[11];
    const float* w2    = (const float*)d_in[12];
    const float* b2    = (const float*)d_in[13];
    const int* srcA = ei;
    const int* dstA = ei + EE;

    char* ws = (char*)d_ws;
    size_t off = 0;
    auto alloc = [&](size_t bytes) -> char* {
        off = (off + 255) & ~(size_t)255;
        char* p = ws + off;
        off += bytes;
        return p;
    };
    int*   deg  = (int*)alloc(NN * 4);
    int*   cnt  = (int*)alloc(NN * 4);
    int*   offs = (int*)alloc((NN + 1) * 4);
    int*   bsum = (int*)alloc(64 * 4);
    int*   perm = (int*)alloc((size_t)EE * 4);
    int*   srcs = (int*)alloc((size_t)EE * 4);
    float* la   = (float*)alloc((size_t)NN * CC * 4);
    unsigned int* eep = (unsigned int*)alloc((size_t)(EE + NN) * 64 * 4);
    float* xl   = (float*)alloc((size_t)NN * DD * 4);
    float* xr   = (float*)alloc((size_t)NN * DD * 4);
    float* bg   = (float*)alloc((size_t)NN * DD * 4);   // GAT layer output
    float* bx   = (float*)alloc((size_t)NN * DD * 4);   // inter-layer x
    float* bh   = xl;                                   // MLP hidden aliases xl (dead after k_gat)

    hipMemsetAsync(deg, 0, NN * 4, stream);
    hipMemsetAsync(cnt, 0, NN * 4, stream);
    k_hist<<<(EE + 255) / 256, 256, 0, stream>>>(dstA, deg);
    int nb = (NN + 1023) / 1024;
    k_scan1<<<nb, 1024, 0, stream>>>(deg, offs, bsum);
    k_scan2<<<1, 64, 0, stream>>>(bsum, nb);
    k_scan3<<<nb, 1024, 0, stream>>>(offs, bsum);
    k_scatter<<<(EE + 255) / 256, 256, 0, stream>>>(srcA, dstA, offs, cnt, perm, srcs);
    k_loopattr<<<(NN * CC + 255) / 256, 256, 0, stream>>>(ea, perm, offs, la);

    const float* x = nodes;
    for (int l = 0; l < LL; l++){
        k_gemm<<<(NN + 63) / 64, 256, 0, stream>>>(x, Wl + l * DD * DD, bl + l * DD, xl, 0);
        k_gemm<<<(NN + 63) / 64, 256, 0, stream>>>(x, Wr + l * DD * DD, br + l * DD, xr, 0);
        k_edgegemm<<<4096, 256, 0, stream>>>(ea, la, perm, We + l * CC * DD, eep);
        k_gat<<<NN / 4, 256, 0, stream>>>(xl, xr, srcs, offs, eep,
                                          att + l * HH * CC, bias + l * DD, bg);
        k_gemm<<<(NN + 63) / 64, 256, 0, stream>>>(bg, w1 + l * DD * DD, b1 + l * DD, bh, 1);
        float* yo = (l == LL - 1) ? (float*)d_out : bx;
        k_gemm<<<(NN + 63) / 64, 256, 0, stream>>>(bh, w2 + l * DD * DD, b2 + l * DD, yo, 0);
        x = bx;
    }
}

// Round 3
// 957.213 us; speedup vs baseline: 1.6660x; 1.2887x over previous
//
#include <hip/hip_runtime.h>
#include <math.h>

#define NN 50000
#define EE 800000
#define DD 128
#define HH 4
#define CC 32
#define LL 2
#define TOT (EE + NN)

typedef __attribute__((ext_vector_type(8))) short short8;
typedef __attribute__((ext_vector_type(4))) float f32x4;

__device__ inline short bf16c(float f){
    unsigned u = __float_as_uint(f);
    u = (u + 0x7fffu + ((u >> 16) & 1u)) >> 16;
    return (short)u;
}

// ---------------- edge sorting (by dst) ----------------

__global__ __launch_bounds__(256) void k_hist(const int* __restrict__ dstA, int* __restrict__ deg){
    int e = blockIdx.x * 256 + threadIdx.x;
    if (e < EE) atomicAdd(&deg[dstA[e]], 1);
}

__global__ __launch_bounds__(1024) void k_scan1(const int* __restrict__ deg, int* __restrict__ offs,
                                                int* __restrict__ bsum){
    __shared__ int buf[1024];
    int t = threadIdx.x;
    int i = blockIdx.x * 1024 + t;
    int v = (i < NN) ? deg[i] : 0;
    buf[t] = v;
    __syncthreads();
    for (int off = 1; off < 1024; off <<= 1){
        int x = (t >= off) ? buf[t - off] : 0;
        __syncthreads();
        buf[t] += x;
        __syncthreads();
    }
    if (i < NN) offs[i + 1] = buf[t];
    if (t == 1023) bsum[blockIdx.x] = buf[1023];
    if (i == 0) offs[0] = 0;
}

__global__ void k_scan2(int* __restrict__ bsum, int nb){
    if (threadIdx.x == 0){
        int s = 0;
        for (int b = 0; b < nb; b++){ int v = bsum[b]; bsum[b] = s; s += v; }
    }
}

__global__ __launch_bounds__(1024) void k_scan3(int* __restrict__ offs, const int* __restrict__ bsum){
    int i = blockIdx.x * 1024 + threadIdx.x;
    if (i < NN) offs[i + 1] += bsum[i >> 10];
}

__global__ __launch_bounds__(256) void k_scatter(const int* __restrict__ srcA, const int* __restrict__ dstA,
                                                 const int* __restrict__ offs, int* __restrict__ cnt,
                                                 int* __restrict__ perm, int* __restrict__ srcs2,
                                                 int* __restrict__ dsts2){
    int e = blockIdx.x * 256 + threadIdx.x;
    if (e < EE){
        int d = dstA[e];
        int pos = offs[d] + atomicAdd(&cnt[d], 1);
        perm[pos] = e;
        srcs2[pos] = srcA[e];
        dsts2[pos] = d;
    }
}

// tail of srcs2/dsts2: self-loop rows
__global__ __launch_bounds__(256) void k_fill(int* __restrict__ srcs2, int* __restrict__ dsts2){
    int i = blockIdx.x * 256 + threadIdx.x;
    if (i < NN){ srcs2[EE + i] = i; dsts2[EE + i] = i; }
}

// loop_attr[n,c] = mean over incoming edges of ea[e,c] (0 if deg==0)
__global__ __launch_bounds__(256) void k_loopattr(const float* __restrict__ ea, const int* __restrict__ perm,
                                                  const int* __restrict__ offs, float* __restrict__ la){
    int tid = blockIdx.x * 256 + threadIdx.x;
    if (tid >= NN * CC) return;
    int n = tid >> 5, c = tid & 31;
    int b = offs[n], e = offs[n + 1];
    float s = 0.f;
    for (int p = b; p < e; ++p) s += ea[perm[p] * CC + c];
    la[tid] = s / fmaxf((float)(e - b), 1.0f);
}

// ---------------- fp32 GEMM: Y[r,c] = act( sum_k X[r,k]*W[k,c] + bv[c] ) ----------------

__global__ __launch_bounds__(256) void k_gemm(const float* __restrict__ X, const float* __restrict__ W,
                                              const float* __restrict__ bv, float* __restrict__ Y, int act){
    __shared__ float Xs[64][33];
    __shared__ float Ws[32][128];
    int tid = threadIdx.x;
    int tx = tid & 15, ty = tid >> 4;
    int r0 = blockIdx.x * 64;
    float acc[4][8];
    #pragma unroll
    for (int i = 0; i < 4; i++)
        #pragma unroll
        for (int j = 0; j < 8; j++) acc[i][j] = 0.f;

    for (int k0 = 0; k0 < 128; k0 += 32){
        {
            int flat = tid * 8;
            int row = flat >> 5;
            int kk = flat & 31;
            int gr = r0 + row; if (gr >= NN) gr = NN - 1;
            const float* s = X + (size_t)gr * 128 + k0 + kk;
            float4 v0 = *(const float4*)s;
            float4 v1 = *(const float4*)(s + 4);
            float* d = &Xs[row][kk];
            d[0]=v0.x; d[1]=v0.y; d[2]=v0.z; d[3]=v0.w;
            d[4]=v1.x; d[5]=v1.y; d[6]=v1.z; d[7]=v1.w;
        }
        {
            int flat = tid * 16;
            int kr = flat >> 7, c = flat & 127;
            const float4* s = (const float4*)(W + (size_t)(k0 + kr) * 128 + c);
            float4* d = (float4*)&Ws[kr][c];
            d[0] = s[0]; d[1] = s[1]; d[2] = s[2]; d[3] = s[3];
        }
        __syncthreads();
        #pragma unroll
        for (int kk = 0; kk < 32; kk++){
            float aa[4];
            #pragma unroll
            for (int i = 0; i < 4; i++) aa[i] = Xs[ty * 4 + i][kk];
            float bb[8];
            *(float4*)&bb[0] = *(float4*)&Ws[kk][tx * 8];
            *(float4*)&bb[4] = *(float4*)&Ws[kk][tx * 8 + 4];
            #pragma unroll
            for (int i = 0; i < 4; i++)
                #pragma unroll
                for (int j = 0; j < 8; j++) acc[i][j] = fmaf(aa[i], bb[j], acc[i][j]);
        }
        __syncthreads();
    }
    #pragma unroll
    for (int i = 0; i < 4; i++){
        int r = r0 + ty * 4 + i;
        if (r < NN){
            #pragma unroll
            for (int j = 0; j < 8; j++){
                int c = tx * 8 + j;
                float v = acc[i][j] + bv[c];
                if (act) v = fmaxf(v, 0.f);
                Y[(size_t)r * 128 + c] = v;
            }
        }
    }
}

// ---------------- fused edge-score kernel (MFMA) ----------------
// For each sorted position pos: ee = ea2[pos] @ We  (MFMA, C[ch][edge] layout),
// then alpha[pos][h] = sum_c att[h,c] * leaky(xl[src][c] + xr[dst][c] + ee[c]).
// One wave handles 16 positions. A = We^T tiles (loop-invariant), B = 16 ea rows.
// C/D layout: col(=edge)=lane&15, row(=channel-in-tile)=(lane>>4)*4+reg [m89].

__global__ __launch_bounds__(256) void k_score(const float* __restrict__ ea, const float* __restrict__ la,
                                               const int* __restrict__ perm, const int* __restrict__ srcs2,
                                               const int* __restrict__ dsts2,
                                               const float* __restrict__ xl, const float* __restrict__ xr,
                                               const float* __restrict__ We, const float* __restrict__ att,
                                               float* __restrict__ alpha){
    const int NG = TOT / 16;   // 53125, exact
    int lane = threadIdx.x & 63;
    int q = lane >> 4;          // 0..3
    int m = lane & 15;          // edge-in-group / A-row

    // preload A-frags: af[t][j] = We[k=8q+j][16t+m]  (A[row=m][k] with row=output channel)
    short8 af[8];
    f32x4 attv[8];
    #pragma unroll
    for (int t = 0; t < 8; t++){
        short v[8];
        #pragma unroll
        for (int j = 0; j < 8; j++)
            v[j] = bf16c(We[(q * 8 + j) * 128 + t * 16 + m]);
        af[t] = short8{v[0],v[1],v[2],v[3],v[4],v[5],v[6],v[7]};
        attv[t] = *(const f32x4*)(att + t * 16 + q * 4);
    }

    int wid = (blockIdx.x * 256 + threadIdx.x) >> 6;
    int nw = (gridDim.x * 256) >> 6;
    for (int g = wid; g < NG; g += nw){
        int pos = g * 16 + m;
        const float* row = (pos < EE) ? ea + (size_t)perm[pos] * 32
                                      : la + (size_t)(pos - EE) * 32;
        f32x4 b0 = *(const f32x4*)(row + q * 8);
        f32x4 b1 = *(const f32x4*)(row + q * 8 + 4);
        short8 bf = short8{bf16c(b0[0]), bf16c(b0[1]), bf16c(b0[2]), bf16c(b0[3]),
                           bf16c(b1[0]), bf16c(b1[1]), bf16c(b1[2]), bf16c(b1[3])};
        int s = srcs2[pos], d = dsts2[pos];
        const float* xls = xl + (size_t)s * 128;
        const float* xrd = xr + (size_t)d * 128;

        float ps[4] = {0.f, 0.f, 0.f, 0.f};
        #pragma unroll
        for (int t = 0; t < 8; t++){
            f32x4 z = {0.f, 0.f, 0.f, 0.f};
            f32x4 c = __builtin_amdgcn_mfma_f32_16x16x32_bf16(af[t], bf, z, 0, 0, 0);
            int ch = t * 16 + q * 4;
            f32x4 xv = *(const f32x4*)(xls + ch);
            f32x4 rv = *(const f32x4*)(xrd + ch);
            #pragma unroll
            for (int r = 0; r < 4; r++){
                float mm = c[r] + xv[r] + rv[r];
                mm = (mm > 0.f) ? mm : 0.2f * mm;
                ps[t >> 1] = fmaf(attv[t][r], mm, ps[t >> 1]);
            }
        }
        // reduce over the 4 lane-groups sharing this edge (lanes m, m+16, m+32, m+48)
        #pragma unroll
        for (int h = 0; h < 4; h++){
            ps[h] += __shfl_xor(ps[h], 16);
            ps[h] += __shfl_xor(ps[h], 32);
        }
        if (lane < 16){
            f32x4 o = {ps[0], ps[1], ps[2], ps[3]};
            *(f32x4*)(alpha + (size_t)pos * 4) = o;
        }
    }
}

// ---------------- GATv2 softmax + aggregation over precomputed logits ----------------
// One wave per node; lane owns channels (lane, lane+64); heads h0=lane>>5, h1=2+h0.

__global__ __launch_bounds__(256) void k_gat2(const float* __restrict__ xl, const int* __restrict__ srcs2,
                                              const int* __restrict__ offs, const float* __restrict__ alpha,
                                              const float* __restrict__ bias, float* __restrict__ out){
    int n = blockIdx.x * 4 + (threadIdx.x >> 6);
    int lane = threadIdx.x & 63;
    int h0 = lane >> 5, h1 = 2 + h0;

    int beg = offs[n];
    int deg = offs[n + 1] - beg;
    int cnt = deg + 1;   // + self-loop (position EE+n, handled by k_score)

    float M0 = -INFINITY, M1 = -INFINITY;
    float S0 = 0.f, S1 = 0.f, A0 = 0.f, A1 = 0.f;

    for (int i = 0; i < cnt; i += 2){
        int pa = (i < deg) ? beg + i : EE + n;
        bool hb = (i + 1) < cnt;
        int pb = ((i + 1) < deg) ? beg + i + 1 : EE + n;

        int sa = srcs2[pa];
        int sb = srcs2[pb];
        float pa0 = alpha[(size_t)pa * 4 + h0], pa1 = alpha[(size_t)pa * 4 + h1];
        float pb0 = alpha[(size_t)pb * 4 + h0], pb1 = alpha[(size_t)pb * 4 + h1];
        float xla0 = xl[(size_t)sa * 128 + lane], xla1 = xl[(size_t)sa * 128 + 64 + lane];
        float xlb0 = xl[(size_t)sb * 128 + lane], xlb1 = xl[(size_t)sb * 128 + 64 + lane];
        if (!hb){ pb0 = -INFINITY; pb1 = -INFINITY; }

        float nM = fmaxf(M0, fmaxf(pa0, pb0));
        float rs = __expf(M0 - nM);
        float wa = __expf(pa0 - nM);
        float wb = __expf(pb0 - nM);
        S0 = S0 * rs + wa + wb;
        A0 = A0 * rs + wa * xla0 + wb * xlb0;
        M0 = nM;

        nM = fmaxf(M1, fmaxf(pa1, pb1));
        rs = __expf(M1 - nM);
        wa = __expf(pa1 - nM);
        wb = __expf(pb1 - nM);
        S1 = S1 * rs + wa + wb;
        A1 = A1 * rs + wa * xlb1 * 0.f + wa * xla1 + wb * xlb1;   // (expanded below)
        M1 = nM;
    }
    out[(size_t)n * 128 + lane]      = A0 / (S0 + 1e-16f) + bias[lane];
    out[(size_t)n * 128 + 64 + lane] = A1 / (S1 + 1e-16f) + bias[64 + lane];
}

// ---------------- driver ----------------

extern "C" void kernel_launch(void* const* d_in, const int* in_sizes, int n_in,
                              void* d_out, int out_size, void* d_ws, size_t ws_size,
                              hipStream_t stream){
    const float* nodes = (const float*)d_in[0];
    const int*   ei    = (const int*)d_in[1];
    const float* ea    = (const float*)d_in[2];
    const float* Wl    = (const float*)d_in[3];
    const float* bl    = (const float*)d_in[4];
    const float* Wr    = (const float*)d_in[5];
    const float* br    = (const float*)d_in[6];
    const float* We    = (const float*)d_in[7];
    const float* att   = (const float*)d_in[8];
    const float* bias  = (const float*)d_in[9];
    const float* w1    = (const float*)d_in[10];
    const float* b1    = (const float*)d_in[11];
    const float* w2    = (const float*)d_in[12];
    const float* b2    = (const float*)d_in[13];
    const int* srcA = ei;
    const int* dstA = ei + EE;

    char* ws = (char*)d_ws;
    size_t off = 0;
    auto alloc = [&](size_t bytes) -> char* {
        off = (off + 255) & ~(size_t)255;
        char* p = ws + off;
        off += bytes;
        return p;
    };
    int*   deg   = (int*)alloc(NN * 4);
    int*   cnt   = (int*)alloc(NN * 4);
    int*   offs  = (int*)alloc((NN + 1) * 4);
    int*   bsum  = (int*)alloc(64 * 4);
    int*   perm  = (int*)alloc((size_t)EE * 4);
    int*   srcs2 = (int*)alloc((size_t)TOT * 4);
    int*   dsts2 = (int*)alloc((size_t)TOT * 4);
    float* la    = (float*)alloc((size_t)NN * CC * 4);
    float* alpha = (float*)alloc((size_t)TOT * 4 * 4);
    float* xl    = (float*)alloc((size_t)NN * DD * 4);
    float* xr    = (float*)alloc((size_t)NN * DD * 4);
    float* bg    = (float*)alloc((size_t)NN * DD * 4);   // GAT layer output
    float* bx    = (float*)alloc((size_t)NN * DD * 4);   // inter-layer x
    float* bh    = xr;   // MLP hidden aliases xr (xr dead after k_score)

    hipMemsetAsync(deg, 0, NN * 4, stream);
    hipMemsetAsync(cnt, 0, NN * 4, stream);
    k_hist<<<(EE + 255) / 256, 256, 0, stream>>>(dstA, deg);
    int nb = (NN + 1023) / 1024;
    k_scan1<<<nb, 1024, 0, stream>>>(deg, offs, bsum);
    k_scan2<<<1, 64, 0, stream>>>(bsum, nb);
    k_scan3<<<nb, 1024, 0, stream>>>(offs, bsum);
    k_scatter<<<(EE + 255) / 256, 256, 0, stream>>>(srcA, dstA, offs, cnt, perm, srcs2, dsts2);
    k_fill<<<(NN + 255) / 256, 256, 0, stream>>>(srcs2, dsts2);
    k_loopattr<<<(NN * CC + 255) / 256, 256, 0, stream>>>(ea, perm, offs, la);

    const float* x = nodes;
    for (int l = 0; l < LL; l++){
        k_gemm<<<(NN + 63) / 64, 256, 0, stream>>>(x, Wl + l * DD * DD, bl + l * DD, xl, 0);
        k_gemm<<<(NN + 63) / 64, 256, 0, stream>>>(x, Wr + l * DD * DD, br + l * DD, xr, 0);
        k_score<<<4096, 256, 0, stream>>>(ea, la, perm, srcs2, dsts2, xl, xr,
                                          We + l * CC * DD, att + l * HH * CC, alpha);
        k_gat2<<<NN / 4, 256, 0, stream>>>(xl, srcs2, offs, alpha, bias + l * DD, bg);
        k_gemm<<<(NN + 63) / 64, 256, 0, stream>>>(bg, w1 + l * DD * DD, b1 + l * DD, bh, 1);
        float* yo = (l == LL - 1) ? (float*)d_out : bx;
        k_gemm<<<(NN + 63) / 64, 256, 0, stream>>>(bh, w2 + l * DD * DD, b2 + l * DD, yo, 0);
        x = bx;
    }
}

// Round 4
// 895.580 us; speedup vs baseline: 1.7806x; 1.0688x over previous
//
#include <hip/hip_runtime.h>
#include <math.h>

#define NN 50000
#define EE 800000
#define DD 128
#define HH 4
#define CC 32
#define LL 2
#define TOT (EE + NN)

typedef __attribute__((ext_vector_type(8))) short short8;
typedef __attribute__((ext_vector_type(4))) short short4v;
typedef __attribute__((ext_vector_type(4))) float f32x4;
typedef __attribute__((ext_vector_type(4))) unsigned short ushort4v;

__device__ inline short bf16c(float f){
    unsigned u = __float_as_uint(f);
    u = (u + 0x7fffu + ((u >> 16) & 1u)) >> 16;
    return (short)u;
}
__device__ inline float bf2f(unsigned short h){
    return __uint_as_float(((unsigned)h) << 16);
}

// ---------------- edge sorting (by dst) ----------------

__global__ __launch_bounds__(256) void k_hist(const int* __restrict__ dstA, int* __restrict__ deg){
    int e = blockIdx.x * 256 + threadIdx.x;
    if (e < EE) atomicAdd(&deg[dstA[e]], 1);
}

__global__ __launch_bounds__(1024) void k_scan1(const int* __restrict__ deg, int* __restrict__ offs,
                                                int* __restrict__ bsum){
    __shared__ int buf[1024];
    int t = threadIdx.x;
    int i = blockIdx.x * 1024 + t;
    int v = (i < NN) ? deg[i] : 0;
    buf[t] = v;
    __syncthreads();
    for (int off = 1; off < 1024; off <<= 1){
        int x = (t >= off) ? buf[t - off] : 0;
        __syncthreads();
        buf[t] += x;
        __syncthreads();
    }
    if (i < NN) offs[i + 1] = buf[t];
    if (t == 1023) bsum[blockIdx.x] = buf[1023];
    if (i == 0) offs[0] = 0;
}

__global__ void k_scan2(int* __restrict__ bsum, int nb){
    if (threadIdx.x == 0){
        int s = 0;
        for (int b = 0; b < nb; b++){ int v = bsum[b]; bsum[b] = s; s += v; }
    }
}

__global__ __launch_bounds__(1024) void k_scan3(int* __restrict__ offs, const int* __restrict__ bsum){
    int i = blockIdx.x * 1024 + threadIdx.x;
    if (i < NN) offs[i + 1] += bsum[i >> 10];
}

__global__ __launch_bounds__(256) void k_scatter(const int* __restrict__ srcA, const int* __restrict__ dstA,
                                                 const int* __restrict__ offs, int* __restrict__ cnt,
                                                 int* __restrict__ perm, int* __restrict__ srcs2,
                                                 int* __restrict__ dsts2){
    int e = blockIdx.x * 256 + threadIdx.x;
    if (e < EE){
        int d = dstA[e];
        int pos = offs[d] + atomicAdd(&cnt[d], 1);
        perm[pos] = e;
        srcs2[pos] = srcA[e];
        dsts2[pos] = d;
    }
}

__global__ __launch_bounds__(256) void k_fill(int* __restrict__ srcs2, int* __restrict__ dsts2){
    int i = blockIdx.x * 256 + threadIdx.x;
    if (i < NN){ srcs2[EE + i] = i; dsts2[EE + i] = i; }
}

// permute ea into dst-sorted order, converting to bf16. thread per (pos, 4-channel quad).
__global__ __launch_bounds__(256) void k_permea(const float* __restrict__ ea, const int* __restrict__ perm,
                                                short* __restrict__ ea2s){
    int tid = blockIdx.x * 256 + threadIdx.x;
    if (tid >= EE * 8) return;
    int pos = tid >> 3, quad = tid & 7;
    f32x4 v = *(const f32x4*)(ea + (size_t)perm[pos] * 32 + quad * 4);
    short4v o = {bf16c(v[0]), bf16c(v[1]), bf16c(v[2]), bf16c(v[3])};
    *(short4v*)(ea2s + (size_t)pos * 32 + quad * 4) = o;
}

// loop_attr rows (appended at ea2s[EE..TOT)): mean of incoming sorted rows, bf16.
__global__ __launch_bounds__(256) void k_loopattr(short* __restrict__ ea2s, const int* __restrict__ offs){
    int tid = blockIdx.x * 256 + threadIdx.x;
    if (tid >= NN * CC) return;
    int n = tid >> 5, c = tid & 31;
    int b = offs[n], e = offs[n + 1];
    float s = 0.f;
    for (int p = b; p < e; ++p) s += bf2f((unsigned short)ea2s[(size_t)p * 32 + c]);
    ea2s[(size_t)(EE + n) * 32 + c] = bf16c(s / fmaxf((float)(e - b), 1.0f));
}

// ---------------- fp32 GEMM: Y[r,c] = act( X@W + bv ), optional f32/bf16 outputs ----------------

__global__ __launch_bounds__(256) void k_gemm(const float* __restrict__ X, const float* __restrict__ W,
                                              const float* __restrict__ bv, float* __restrict__ Yf,
                                              unsigned short* __restrict__ Yh, int act, int mode){
    __shared__ float Xs[64][33];
    __shared__ float Ws[32][128];
    int tid = threadIdx.x;
    int tx = tid & 15, ty = tid >> 4;
    int r0 = blockIdx.x * 64;
    float acc[4][8];
    #pragma unroll
    for (int i = 0; i < 4; i++)
        #pragma unroll
        for (int j = 0; j < 8; j++) acc[i][j] = 0.f;

    for (int k0 = 0; k0 < 128; k0 += 32){
        {
            int flat = tid * 8;
            int row = flat >> 5;
            int kk = flat & 31;
            int gr = r0 + row; if (gr >= NN) gr = NN - 1;
            const float* s = X + (size_t)gr * 128 + k0 + kk;
            float4 v0 = *(const float4*)s;
            float4 v1 = *(const float4*)(s + 4);
            float* d = &Xs[row][kk];
            d[0]=v0.x; d[1]=v0.y; d[2]=v0.z; d[3]=v0.w;
            d[4]=v1.x; d[5]=v1.y; d[6]=v1.z; d[7]=v1.w;
        }
        {
            int flat = tid * 16;
            int kr = flat >> 7, c = flat & 127;
            const float4* s = (const float4*)(W + (size_t)(k0 + kr) * 128 + c);
            float4* d = (float4*)&Ws[kr][c];
            d[0] = s[0]; d[1] = s[1]; d[2] = s[2]; d[3] = s[3];
        }
        __syncthreads();
        #pragma unroll
        for (int kk = 0; kk < 32; kk++){
            float aa[4];
            #pragma unroll
            for (int i = 0; i < 4; i++) aa[i] = Xs[ty * 4 + i][kk];
            float bb[8];
            *(float4*)&bb[0] = *(float4*)&Ws[kk][tx * 8];
            *(float4*)&bb[4] = *(float4*)&Ws[kk][tx * 8 + 4];
            #pragma unroll
            for (int i = 0; i < 4; i++)
                #pragma unroll
                for (int j = 0; j < 8; j++) acc[i][j] = fmaf(aa[i], bb[j], acc[i][j]);
        }
        __syncthreads();
    }
    #pragma unroll
    for (int i = 0; i < 4; i++){
        int r = r0 + ty * 4 + i;
        if (r < NN){
            float vv[8];
            #pragma unroll
            for (int j = 0; j < 8; j++){
                float v = acc[i][j] + bv[tx * 8 + j];
                if (act) v = fmaxf(v, 0.f);
                vv[j] = v;
            }
            if (mode & 1){
                float* p = Yf + (size_t)r * 128 + tx * 8;
                *(float4*)p = *(float4*)&vv[0];
                *(float4*)(p + 4) = *(float4*)&vv[4];
            }
            if (mode & 2){
                short8 h = {bf16c(vv[0]), bf16c(vv[1]), bf16c(vv[2]), bf16c(vv[3]),
                            bf16c(vv[4]), bf16c(vv[5]), bf16c(vv[6]), bf16c(vv[7])};
                *(short8*)(Yh + (size_t)r * 128 + tx * 8) = h;
            }
        }
    }
}

// ---------------- fused edge-score kernel (MFMA over sequential bf16 rows) ----------------
// alpha[pos][h] = sum_c att[h,c] * leaky(xl[src][c] + xr[dst][c] + (ea2s[pos]@We)[c])
// One wave per 16 positions. C/D layout: col(edge)=lane&15, row(ch)=(lane>>4)*4+reg.

__global__ __launch_bounds__(256) void k_score(const short* __restrict__ ea2s,
                                               const int* __restrict__ srcs2, const int* __restrict__ dsts2,
                                               const unsigned short* __restrict__ xlb,
                                               const unsigned short* __restrict__ xrb,
                                               const float* __restrict__ We, const float* __restrict__ att,
                                               float* __restrict__ alpha){
    const int NG = TOT / 16;   // 53125, exact
    int lane = threadIdx.x & 63;
    int q = lane >> 4;          // 0..3
    int m = lane & 15;          // edge-in-group / A-row

    short8 af[8];
    f32x4 attv[8];
    #pragma unroll
    for (int t = 0; t < 8; t++){
        short v[8];
        #pragma unroll
        for (int j = 0; j < 8; j++)
            v[j] = bf16c(We[(q * 8 + j) * 128 + t * 16 + m]);
        af[t] = short8{v[0],v[1],v[2],v[3],v[4],v[5],v[6],v[7]};
        attv[t] = *(const f32x4*)(att + t * 16 + q * 4);
    }

    int wid = (blockIdx.x * 256 + threadIdx.x) >> 6;
    int nw = (gridDim.x * 256) >> 6;
    for (int g = wid; g < NG; g += nw){
        int pos = g * 16 + m;
        short8 bf = *(const short8*)(ea2s + (size_t)pos * 32 + q * 8);
        int s = srcs2[pos], d = dsts2[pos];
        const unsigned short* xls = xlb + (size_t)s * 128;
        const unsigned short* xrd = xrb + (size_t)d * 128;

        float ps[4] = {0.f, 0.f, 0.f, 0.f};
        #pragma unroll
        for (int t = 0; t < 8; t++){
            f32x4 z = {0.f, 0.f, 0.f, 0.f};
            f32x4 c = __builtin_amdgcn_mfma_f32_16x16x32_bf16(af[t], bf, z, 0, 0, 0);
            int ch = t * 16 + q * 4;
            ushort4v xv = *(const ushort4v*)(xls + ch);
            ushort4v rv = *(const ushort4v*)(xrd + ch);
            #pragma unroll
            for (int r = 0; r < 4; r++){
                float mm = c[r] + bf2f(xv[r]) + bf2f(rv[r]);
                mm = (mm > 0.f) ? mm : 0.2f * mm;
                ps[t >> 1] = fmaf(attv[t][r], mm, ps[t >> 1]);
            }
        }
        #pragma unroll
        for (int h = 0; h < 4; h++){
            ps[h] += __shfl_xor(ps[h], 16);
            ps[h] += __shfl_xor(ps[h], 32);
        }
        if (lane < 16){
            f32x4 o = {ps[0], ps[1], ps[2], ps[3]};
            *(f32x4*)(alpha + (size_t)pos * 4) = o;
        }
    }
}

// ---------------- GATv2 softmax + aggregation over precomputed logits ----------------

__global__ __launch_bounds__(256) void k_gat2(const float* __restrict__ xl, const int* __restrict__ srcs2,
                                              const int* __restrict__ offs, const float* __restrict__ alpha,
                                              const float* __restrict__ bias, float* __restrict__ out){
    int n = blockIdx.x * 4 + (threadIdx.x >> 6);
    int lane = threadIdx.x & 63;
    int h0 = lane >> 5, h1 = 2 + h0;

    int beg = offs[n];
    int deg = offs[n + 1] - beg;
    int cnt = deg + 1;   // + self-loop (position EE+n)

    float M0 = -INFINITY, M1 = -INFINITY;
    float S0 = 0.f, S1 = 0.f, A0 = 0.f, A1 = 0.f;

    for (int i = 0; i < cnt; i += 2){
        int pa = (i < deg) ? beg + i : EE + n;
        bool hb = (i + 1) < cnt;
        int pb = ((i + 1) < deg) ? beg + i + 1 : EE + n;

        int sa = srcs2[pa];
        int sb = srcs2[pb];
        float pa0 = alpha[(size_t)pa * 4 + h0], pa1 = alpha[(size_t)pa * 4 + h1];
        float pb0 = alpha[(size_t)pb * 4 + h0], pb1 = alpha[(size_t)pb * 4 + h1];
        float xla0 = xl[(size_t)sa * 128 + lane], xla1 = xl[(size_t)sa * 128 + 64 + lane];
        float xlb0 = xl[(size_t)sb * 128 + lane], xlb1 = xl[(size_t)sb * 128 + 64 + lane];
        if (!hb){ pb0 = -INFINITY; pb1 = -INFINITY; }

        float nM = fmaxf(M0, fmaxf(pa0, pb0));
        float rs = __expf(M0 - nM);
        float wa = __expf(pa0 - nM);
        float wb = __expf(pb0 - nM);
        S0 = S0 * rs + wa + wb;
        A0 = A0 * rs + wa * xla0 + wb * xlb0;
        M0 = nM;

        nM = fmaxf(M1, fmaxf(pa1, pb1));
        rs = __expf(M1 - nM);
        wa = __expf(pa1 - nM);
        wb = __expf(pb1 - nM);
        S1 = S1 * rs + wa + wb;
        A1 = A1 * rs + wa * xla1 + wb * xlb1;
        M1 = nM;
    }
    out[(size_t)n * 128 + lane]      = A0 / (S0 + 1e-16f) + bias[lane];
    out[(size_t)n * 128 + 64 + lane] = A1 / (S1 + 1e-16f) + bias[64 + lane];
}

// ---------------- driver ----------------

extern "C" void kernel_launch(void* const* d_in, const int* in_sizes, int n_in,
                              void* d_out, int out_size, void* d_ws, size_t ws_size,
                              hipStream_t stream){
    const float* nodes = (const float*)d_in[0];
    const int*   ei    = (const int*)d_in[1];
    const float* ea    = (const float*)d_in[2];
    const float* Wl    = (const float*)d_in[3];
    const float* bl    = (const float*)d_in[4];
    const float* Wr    = (const float*)d_in[5];
    const float* br    = (const float*)d_in[6];
    const float* We    = (const float*)d_in[7];
    const float* att   = (const float*)d_in[8];
    const float* bias  = (const float*)d_in[9];
    const float* w1    = (const float*)d_in[10];
    const float* b1    = (const float*)d_in[11];
    const float* w2    = (const float*)d_in[12];
    const float* b2    = (const float*)d_in[13];
    const int* srcA = ei;
    const int* dstA = ei + EE;

    char* ws = (char*)d_ws;
    size_t off = 0;
    auto alloc = [&](size_t bytes) -> char* {
        off = (off + 255) & ~(size_t)255;
        char* p = ws + off;
        off += bytes;
        return p;
    };
    int*   deg   = (int*)alloc(NN * 4);
    int*   cnt   = (int*)alloc(NN * 4);
    int*   offs  = (int*)alloc((NN + 1) * 4);
    int*   bsum  = (int*)alloc(64 * 4);
    int*   perm  = (int*)alloc((size_t)EE * 4);
    int*   srcs2 = (int*)alloc((size_t)TOT * 4);
    int*   dsts2 = (int*)alloc((size_t)TOT * 4);
    short* ea2s  = (short*)alloc((size_t)TOT * CC * 2);         // sorted bf16 edge attrs + loop rows
    float* alpha = (float*)alloc((size_t)TOT * 4 * 4);
    float* xl    = (float*)alloc((size_t)NN * DD * 4);          // fp32 (aggregation values)
    unsigned short* xlb = (unsigned short*)alloc((size_t)NN * DD * 2);
    unsigned short* xrb = (unsigned short*)alloc((size_t)NN * DD * 2);
    float* bg    = (float*)alloc((size_t)NN * DD * 4);
    float* bx    = (float*)alloc((size_t)NN * DD * 4);
    float* bh    = xl;   // MLP hidden aliases xl (dead after k_gat2)

    hipMemsetAsync(deg, 0, NN * 4, stream);
    hipMemsetAsync(cnt, 0, NN * 4, stream);
    k_hist<<<(EE + 255) / 256, 256, 0, stream>>>(dstA, deg);
    int nb = (NN + 1023) / 1024;
    k_scan1<<<nb, 1024, 0, stream>>>(deg, offs, bsum);
    k_scan2<<<1, 64, 0, stream>>>(bsum, nb);
    k_scan3<<<nb, 1024, 0, stream>>>(offs, bsum);
    k_scatter<<<(EE + 255) / 256, 256, 0, stream>>>(srcA, dstA, offs, cnt, perm, srcs2, dsts2);
    k_fill<<<(NN + 255) / 256, 256, 0, stream>>>(srcs2, dsts2);
    k_permea<<<(EE * 8 + 255) / 256, 256, 0, stream>>>(ea, perm, ea2s);
    k_loopattr<<<(NN * CC + 255) / 256, 256, 0, stream>>>(ea2s, offs);

    const float* x = nodes;
    for (int l = 0; l < LL; l++){
        k_gemm<<<(NN + 63) / 64, 256, 0, stream>>>(x, Wl + l * DD * DD, bl + l * DD, xl, xlb, 0, 3);
        k_gemm<<<(NN + 63) / 64, 256, 0, stream>>>(x, Wr + l * DD * DD, br + l * DD, bg, xrb, 0, 2);
        k_score<<<4096, 256, 0, stream>>>(ea2s, srcs2, dsts2, xlb, xrb,
                                          We + l * CC * DD, att + l * HH * CC, alpha);
        k_gat2<<<NN / 4, 256, 0, stream>>>(xl, srcs2, offs, alpha, bias + l * DD, bg);
        k_gemm<<<(NN + 63) / 64, 256, 0, stream>>>(bg, w1 + l * DD * DD, b1 + l * DD, bh, xlb, 1, 1);
        float* yo = (l == LL - 1) ? (float*)d_out : bx;
        k_gemm<<<(NN + 63) / 64, 256, 0, stream>>>(bh, w2 + l * DD * DD, b2 + l * DD, yo, xlb, 0, 1);
        x = bx;
    }
}

// Round 5
// 744.055 us; speedup vs baseline: 2.1432x; 1.2036x over previous
//
#include <hip/hip_runtime.h>
#include <math.h>

#define NN 50000
#define EE 800000
#define DD 128
#define HH 4
#define CC 32
#define LL 2
#define TOT (EE + NN)

typedef __attribute__((ext_vector_type(8))) short short8;
typedef __attribute__((ext_vector_type(4))) short short4v;
typedef __attribute__((ext_vector_type(4))) float f32x4;
typedef __attribute__((ext_vector_type(4))) unsigned short ushort4v;

__device__ inline short bf16c(float f){
    unsigned u = __float_as_uint(f);
    u = (u + 0x7fffu + ((u >> 16) & 1u)) >> 16;
    return (short)u;
}
__device__ inline float bf2f(unsigned short h){
    return __uint_as_float(((unsigned)h) << 16);
}

// ---------------- edge sorting (by dst) ----------------

__global__ __launch_bounds__(256) void k_hist(const int* __restrict__ dstA, int* __restrict__ deg){
    int e = blockIdx.x * 256 + threadIdx.x;
    if (e < EE) atomicAdd(&deg[dstA[e]], 1);
}

__global__ __launch_bounds__(1024) void k_scan1(const int* __restrict__ deg, int* __restrict__ offs,
                                                int* __restrict__ bsum){
    __shared__ int buf[1024];
    int t = threadIdx.x;
    int i = blockIdx.x * 1024 + t;
    int v = (i < NN) ? deg[i] : 0;
    buf[t] = v;
    __syncthreads();
    for (int off = 1; off < 1024; off <<= 1){
        int x = (t >= off) ? buf[t - off] : 0;
        __syncthreads();
        buf[t] += x;
        __syncthreads();
    }
    if (i < NN) offs[i + 1] = buf[t];
    if (t == 1023) bsum[blockIdx.x] = buf[1023];
    if (i == 0) offs[0] = 0;
}

__global__ void k_scan2(int* __restrict__ bsum, int nb){
    if (threadIdx.x == 0){
        int s = 0;
        for (int b = 0; b < nb; b++){ int v = bsum[b]; bsum[b] = s; s += v; }
    }
}

__global__ __launch_bounds__(1024) void k_scan3(int* __restrict__ offs, const int* __restrict__ bsum){
    int i = blockIdx.x * 1024 + threadIdx.x;
    if (i < NN) offs[i + 1] += bsum[i >> 10];
}

// scatter: sort edges by dst; also permute+convert edge_attr rows to bf16 in sorted order
__global__ __launch_bounds__(256) void k_scatter(const int* __restrict__ srcA, const int* __restrict__ dstA,
                                                 const float* __restrict__ ea,
                                                 const int* __restrict__ offs, int* __restrict__ cnt,
                                                 int* __restrict__ srcs2, int* __restrict__ dsts2,
                                                 short* __restrict__ ea2s){
    int e = blockIdx.x * 256 + threadIdx.x;
    if (e < EE){
        int d = dstA[e];
        int pos = offs[d] + atomicAdd(&cnt[d], 1);
        srcs2[pos] = srcA[e];
        dsts2[pos] = d;
        const float* r = ea + (size_t)e * 32;
        short* o = ea2s + (size_t)pos * 32;
        #pragma unroll
        for (int qd = 0; qd < 8; qd++){
            f32x4 v = *(const f32x4*)(r + qd * 4);
            short4v h = {bf16c(v[0]), bf16c(v[1]), bf16c(v[2]), bf16c(v[3])};
            *(short4v*)(o + qd * 4) = h;
        }
    }
}

__global__ __launch_bounds__(256) void k_fill(int* __restrict__ srcs2, int* __restrict__ dsts2){
    int i = blockIdx.x * 256 + threadIdx.x;
    if (i < NN){ srcs2[EE + i] = i; dsts2[EE + i] = i; }
}

// loop_attr rows (appended at ea2s[EE..TOT)): mean of incoming sorted rows, bf16.
__global__ __launch_bounds__(256) void k_loopattr(short* __restrict__ ea2s, const int* __restrict__ offs){
    int tid = blockIdx.x * 256 + threadIdx.x;
    if (tid >= NN * CC) return;
    int n = tid >> 5, c = tid & 31;
    int b = offs[n], e = offs[n + 1];
    float s = 0.f;
    for (int p = b; p < e; ++p) s += bf2f((unsigned short)ea2s[(size_t)p * 32 + c]);
    ea2s[(size_t)(EE + n) * 32 + c] = bf16c(s / fmaxf((float)(e - b), 1.0f));
}

// ---------------- weight prep: Wt[c][k] = bf16(W[k][c]) for the 8 DxD matrices ----------------
// order: Wl0,Wl1,Wr0,Wr1,w10,w11,w20,w21

__global__ __launch_bounds__(256) void k_prepw(const float* __restrict__ Wl, const float* __restrict__ Wr,
                                               const float* __restrict__ w1, const float* __restrict__ w2,
                                               short* __restrict__ wt){
    int gid = blockIdx.x * 256 + threadIdx.x;      // 8 * 16384
    int mi = gid >> 14;
    int flat = gid & 16383;
    const float* base = (mi < 2) ? Wl : (mi < 4) ? Wr : (mi < 6) ? w1 : w2;
    const float* src = base + (size_t)(mi & 1) * 16384;
    int k = flat >> 7, c = flat & 127;
    wt[(size_t)mi * 16384 + c * 128 + k] = bf16c(src[flat]);
}

// nodes fp32 -> bf16
__global__ __launch_bounds__(256) void k_prepx(const float* __restrict__ x, short* __restrict__ xb){
    int i = blockIdx.x * 256 + threadIdx.x;        // over NN*DD/4
    if (i >= NN * DD / 4) return;
    f32x4 v = *(const f32x4*)(x + (size_t)i * 4);
    short4v h = {bf16c(v[0]), bf16c(v[1]), bf16c(v[2]), bf16c(v[3])};
    *(short4v*)(xb + (size_t)i * 4) = h;
}

// ---------------- MFMA GEMM: C[r][c] = act( sum_k X[r][k] W[k][c] + bias[c] ) ----------------
// A = W^T (A[m=c][k], from wt, 16B reg frags loaded once), B = X^T (B[k][n=r], 16B global loads).
// D: n(=row r)=lane&15, m(=col c)=(lane>>4)*4+reg. Wave w handles cols [32w,32w+32); block: 64 rows.

__global__ __launch_bounds__(256) void k_mg(const short* __restrict__ Xb, const short* __restrict__ Wt,
                                            const float* __restrict__ bv, float* __restrict__ Yf,
                                            unsigned short* __restrict__ Yb, int act, int mode){
    int lane = threadIdx.x & 63;
    int wave = threadIdx.x >> 6;
    int q = lane >> 4;
    int m = lane & 15;
    int cw0 = wave * 32;
    int r0 = blockIdx.x * 64;

    short8 af[2][4];
    #pragma unroll
    for (int ct = 0; ct < 2; ct++)
        #pragma unroll
        for (int ks = 0; ks < 4; ks++)
            af[ct][ks] = *(const short8*)(Wt + (size_t)(cw0 + ct * 16 + m) * 128 + ks * 32 + q * 8);

    f32x4 bq[2];
    #pragma unroll
    for (int ct = 0; ct < 2; ct++)
        bq[ct] = *(const f32x4*)(bv + cw0 + ct * 16 + q * 4);

    #pragma unroll
    for (int rt = 0; rt < 4; rt++){
        int r = r0 + rt * 16 + m;
        int rc = (r < NN) ? r : NN - 1;
        short8 bf[4];
        #pragma unroll
        for (int ks = 0; ks < 4; ks++)
            bf[ks] = *(const short8*)(Xb + (size_t)rc * 128 + ks * 32 + q * 8);

        f32x4 ac0 = {0.f, 0.f, 0.f, 0.f};
        f32x4 ac1 = {0.f, 0.f, 0.f, 0.f};
        #pragma unroll
        for (int ks = 0; ks < 4; ks++){
            ac0 = __builtin_amdgcn_mfma_f32_16x16x32_bf16(af[0][ks], bf[ks], ac0, 0, 0, 0);
            ac1 = __builtin_amdgcn_mfma_f32_16x16x32_bf16(af[1][ks], bf[ks], ac1, 0, 0, 0);
        }
        // lane holds C[row = r0+rt*16 + (lane&15)][cols cw0+ct*16+q*4 .. +3]
        int rr = r0 + rt * 16 + m;
        if (rr < NN){
            #pragma unroll
            for (int ct = 0; ct < 2; ct++){
                f32x4 a = ct ? ac1 : ac0;
                f32x4 v;
                #pragma unroll
                for (int j = 0; j < 4; j++){
                    float x = a[j] + bq[ct][j];
                    if (act) x = fmaxf(x, 0.f);
                    v[j] = x;
                }
                int c0 = cw0 + ct * 16 + q * 4;
                if (mode & 1)
                    *(f32x4*)(Yf + (size_t)rr * 128 + c0) = v;
                if (mode & 2){
                    short4v h = {bf16c(v[0]), bf16c(v[1]), bf16c(v[2]), bf16c(v[3])};
                    *(short4v*)(Yb + (size_t)rr * 128 + c0) = h;
                }
            }
        }
    }
}

// ---------------- fused edge-score kernel (MFMA over sequential bf16 rows) ----------------

__global__ __launch_bounds__(256) void k_score(const short* __restrict__ ea2s,
                                               const int* __restrict__ srcs2, const int* __restrict__ dsts2,
                                               const unsigned short* __restrict__ xlb,
                                               const unsigned short* __restrict__ xrb,
                                               const float* __restrict__ We, const float* __restrict__ att,
                                               float* __restrict__ alpha){
    const int NG = TOT / 16;   // 53125, exact
    int lane = threadIdx.x & 63;
    int q = lane >> 4;
    int m = lane & 15;

    short8 af[8];
    f32x4 attv[8];
    #pragma unroll
    for (int t = 0; t < 8; t++){
        short v[8];
        #pragma unroll
        for (int j = 0; j < 8; j++)
            v[j] = bf16c(We[(q * 8 + j) * 128 + t * 16 + m]);
        af[t] = short8{v[0],v[1],v[2],v[3],v[4],v[5],v[6],v[7]};
        attv[t] = *(const f32x4*)(att + t * 16 + q * 4);
    }

    int wid = (blockIdx.x * 256 + threadIdx.x) >> 6;
    int nw = (gridDim.x * 256) >> 6;
    for (int g = wid; g < NG; g += nw){
        int pos = g * 16 + m;
        short8 bf = *(const short8*)(ea2s + (size_t)pos * 32 + q * 8);
        int s = srcs2[pos], d = dsts2[pos];
        const unsigned short* xls = xlb + (size_t)s * 128;
        const unsigned short* xrd = xrb + (size_t)d * 128;

        float ps[4] = {0.f, 0.f, 0.f, 0.f};
        #pragma unroll
        for (int t = 0; t < 8; t++){
            f32x4 z = {0.f, 0.f, 0.f, 0.f};
            f32x4 c = __builtin_amdgcn_mfma_f32_16x16x32_bf16(af[t], bf, z, 0, 0, 0);
            int ch = t * 16 + q * 4;
            ushort4v xv = *(const ushort4v*)(xls + ch);
            ushort4v rv = *(const ushort4v*)(xrd + ch);
            #pragma unroll
            for (int r = 0; r < 4; r++){
                float mm = c[r] + bf2f(xv[r]) + bf2f(rv[r]);
                mm = (mm > 0.f) ? mm : 0.2f * mm;
                ps[t >> 1] = fmaf(attv[t][r], mm, ps[t >> 1]);
            }
        }
        #pragma unroll
        for (int h = 0; h < 4; h++){
            ps[h] += __shfl_xor(ps[h], 16);
            ps[h] += __shfl_xor(ps[h], 32);
        }
        if (lane < 16){
            f32x4 o = {ps[0], ps[1], ps[2], ps[3]};
            *(f32x4*)(alpha + (size_t)pos * 4) = o;
        }
    }
}

// ---------------- GATv2 softmax + aggregation over precomputed logits ----------------
// out: bf16 (feeds the MLP MFMA GEMM)

__global__ __launch_bounds__(256) void k_gat2(const float* __restrict__ xl, const int* __restrict__ srcs2,
                                              const int* __restrict__ offs, const float* __restrict__ alpha,
                                              const float* __restrict__ bias, unsigned short* __restrict__ out){
    int n = blockIdx.x * 4 + (threadIdx.x >> 6);
    int lane = threadIdx.x & 63;
    int h0 = lane >> 5, h1 = 2 + h0;

    int beg = offs[n];
    int deg = offs[n + 1] - beg;
    int cnt = deg + 1;   // + self-loop (position EE+n)

    float M0 = -INFINITY, M1 = -INFINITY;
    float S0 = 0.f, S1 = 0.f, A0 = 0.f, A1 = 0.f;

    for (int i = 0; i < cnt; i += 2){
        int pa = (i < deg) ? beg + i : EE + n;
        bool hb = (i + 1) < cnt;
        int pb = ((i + 1) < deg) ? beg + i + 1 : EE + n;

        int sa = srcs2[pa];
        int sb = srcs2[pb];
        float pa0 = alpha[(size_t)pa * 4 + h0], pa1 = alpha[(size_t)pa * 4 + h1];
        float pb0 = alpha[(size_t)pb * 4 + h0], pb1 = alpha[(size_t)pb * 4 + h1];
        float xla0 = xl[(size_t)sa * 128 + lane], xla1 = xl[(size_t)sa * 128 + 64 + lane];
        float xlb0 = xl[(size_t)sb * 128 + lane], xlb1 = xl[(size_t)sb * 128 + 64 + lane];
        if (!hb){ pb0 = -INFINITY; pb1 = -INFINITY; }

        float nM = fmaxf(M0, fmaxf(pa0, pb0));
        float rs = __expf(M0 - nM);
        float wa = __expf(pa0 - nM);
        float wb = __expf(pb0 - nM);
        S0 = S0 * rs + wa + wb;
        A0 = A0 * rs + wa * xla0 + wb * xlb0;
        M0 = nM;

        nM = fmaxf(M1, fmaxf(pa1, pb1));
        rs = __expf(M1 - nM);
        wa = __expf(pa1 - nM);
        wb = __expf(pb1 - nM);
        S1 = S1 * rs + wa + wb;
        A1 = A1 * rs + wa * xla1 + wb * xlb1;
        M1 = nM;
    }
    out[(size_t)n * 128 + lane]      = (unsigned short)bf16c(A0 / (S0 + 1e-16f) + bias[lane]);
    out[(size_t)n * 128 + 64 + lane] = (unsigned short)bf16c(A1 / (S1 + 1e-16f) + bias[64 + lane]);
}

// ---------------- driver ----------------

extern "C" void kernel_launch(void* const* d_in, const int* in_sizes, int n_in,
                              void* d_out, int out_size, void* d_ws, size_t ws_size,
                              hipStream_t stream){
    const float* nodes = (const float*)d_in[0];
    const int*   ei    = (const int*)d_in[1];
    const float* ea    = (const float*)d_in[2];
    const float* Wl    = (const float*)d_in[3];
    const float* bl    = (const float*)d_in[4];
    const float* Wr    = (const float*)d_in[5];
    const float* br    = (const float*)d_in[6];
    const float* We    = (const float*)d_in[7];
    const float* att   = (const float*)d_in[8];
    const float* bias  = (const float*)d_in[9];
    const float* w1    = (const float*)d_in[10];
    const float* b1    = (const float*)d_in[11];
    const float* w2    = (const float*)d_in[12];
    const float* b2    = (const float*)d_in[13];
    const int* srcA = ei;
    const int* dstA = ei + EE;

    char* ws = (char*)d_ws;
    size_t off = 0;
    auto alloc = [&](size_t bytes) -> char* {
        off = (off + 255) & ~(size_t)255;
        char* p = ws + off;
        off += bytes;
        return p;
    };
    int*   deg   = (int*)alloc(NN * 4);
    int*   cnt   = (int*)alloc(NN * 4);
    int*   offs  = (int*)alloc((NN + 1) * 4);
    int*   bsum  = (int*)alloc(64 * 4);
    int*   srcs2 = (int*)alloc((size_t)TOT * 4);
    int*   dsts2 = (int*)alloc((size_t)TOT * 4);
    short* ea2s  = (short*)alloc((size_t)TOT * CC * 2);
    float* alpha = (float*)alloc((size_t)TOT * 4 * 4);
    short* wt    = (short*)alloc((size_t)8 * 16384 * 2);          // 8 transposed bf16 weights
    short* xb    = (short*)alloc((size_t)NN * DD * 2);            // current x, bf16
    float* xl    = (float*)alloc((size_t)NN * DD * 4);            // fp32 xl (aggregation values)
    unsigned short* xlb = (unsigned short*)alloc((size_t)NN * DD * 2);
    unsigned short* xrb = (unsigned short*)alloc((size_t)NN * DD * 2);
    unsigned short* bgb = (unsigned short*)alloc((size_t)NN * DD * 2);  // gat2 out, bf16
    unsigned short* bhb = (unsigned short*)alloc((size_t)NN * DD * 2);  // MLP hidden, bf16
    unsigned short* bxb = (unsigned short*)alloc((size_t)NN * DD * 2);  // inter-layer x, bf16

    hipMemsetAsync(deg, 0, NN * 4, stream);
    hipMemsetAsync(cnt, 0, NN * 4, stream);
    k_hist<<<(EE + 255) / 256, 256, 0, stream>>>(dstA, deg);
    int nb = (NN + 1023) / 1024;
    k_scan1<<<nb, 1024, 0, stream>>>(deg, offs, bsum);
    k_scan2<<<1, 64, 0, stream>>>(bsum, nb);
    k_scan3<<<nb, 1024, 0, stream>>>(offs, bsum);
    k_scatter<<<(EE + 255) / 256, 256, 0, stream>>>(srcA, dstA, ea, offs, cnt, srcs2, dsts2, ea2s);
    k_fill<<<(NN + 255) / 256, 256, 0, stream>>>(srcs2, dsts2);
    k_loopattr<<<(NN * CC + 255) / 256, 256, 0, stream>>>(ea2s, offs);
    k_prepw<<<8 * 16384 / 256, 256, 0, stream>>>(Wl, Wr, w1, w2, wt);
    k_prepx<<<(NN * DD / 4 + 255) / 256, 256, 0, stream>>>(nodes, xb);

    const int GB = (NN + 63) / 64;   // 782
    short* wtWl = wt;
    short* wtWr = wt + 2 * 16384;
    short* wtw1 = wt + 4 * 16384;
    short* wtw2 = wt + 6 * 16384;

    const short* x = xb;
    for (int l = 0; l < LL; l++){
        k_mg<<<GB, 256, 0, stream>>>(x, wtWl + l * 16384, bl + l * DD, xl, xlb, 0, 3);
        k_mg<<<GB, 256, 0, stream>>>(x, wtWr + l * 16384, br + l * DD, nullptr, xrb, 0, 2);
        k_score<<<4096, 256, 0, stream>>>(ea2s, srcs2, dsts2, xlb, xrb,
                                          We + l * CC * DD, att + l * HH * CC, alpha);
        k_gat2<<<NN / 4, 256, 0, stream>>>(xl, srcs2, offs, alpha, bias + l * DD, bgb);
        k_mg<<<GB, 256, 0, stream>>>((const short*)bgb, wtw1 + l * 16384, b1 + l * DD, nullptr, bhb, 1, 2);
        if (l == LL - 1)
            k_mg<<<GB, 256, 0, stream>>>((const short*)bhb, wtw2 + l * 16384, b2 + l * DD,
                                         (float*)d_out, nullptr, 0, 1);
        else
            k_mg<<<GB, 256, 0, stream>>>((const short*)bhb, wtw2 + l * 16384, b2 + l * DD,
                                         nullptr, bxb, 0, 2);
        x = (const short*)bxb;
    }
}

// Round 6
// 689.109 us; speedup vs baseline: 2.3141x; 1.0797x over previous
//
#include <hip/hip_runtime.h>
#include <math.h>

#define NN 50000
#define EE 800000
#define DD 128
#define HH 4
#define CC 32
#define LL 2
#define TOT (EE + NN)
#define NG (TOT / 16)

typedef __attribute__((ext_vector_type(8))) short short8;
typedef __attribute__((ext_vector_type(4))) short short4v;
typedef __attribute__((ext_vector_type(4))) float f32x4;
typedef __attribute__((ext_vector_type(4))) unsigned short ushort4v;

__device__ inline short bf16c(float f){
    unsigned u = __float_as_uint(f);
    u = (u + 0x7fffu + ((u >> 16) & 1u)) >> 16;
    return (short)u;
}
__device__ inline float bf2f(unsigned short h){
    return __uint_as_float(((unsigned)h) << 16);
}

// ---------------- edge sorting (by dst) ----------------

__global__ __launch_bounds__(256) void k_hist(const int* __restrict__ dstA, int* __restrict__ deg){
    int e = blockIdx.x * 256 + threadIdx.x;
    if (e < EE) atomicAdd(&deg[dstA[e]], 1);
}

__global__ __launch_bounds__(1024) void k_scan1(const int* __restrict__ deg, int* __restrict__ offs,
                                                int* __restrict__ bsum){
    __shared__ int buf[1024];
    int t = threadIdx.x;
    int i = blockIdx.x * 1024 + t;
    int v = (i < NN) ? deg[i] : 0;
    buf[t] = v;
    __syncthreads();
    for (int off = 1; off < 1024; off <<= 1){
        int x = (t >= off) ? buf[t - off] : 0;
        __syncthreads();
        buf[t] += x;
        __syncthreads();
    }
    if (i < NN) offs[i + 1] = buf[t];
    if (t == 1023) bsum[blockIdx.x] = buf[1023];
    if (i == 0) offs[0] = 0;
}

__global__ void k_scan2(int* __restrict__ bsum, int nb){
    if (threadIdx.x == 0){
        int s = 0;
        for (int b = 0; b < nb; b++){ int v = bsum[b]; bsum[b] = s; s += v; }
    }
}

__global__ __launch_bounds__(1024) void k_scan3(int* __restrict__ offs, const int* __restrict__ bsum){
    int i = blockIdx.x * 1024 + threadIdx.x;
    if (i < NN) offs[i + 1] += bsum[i >> 10];
}

// scatter: sort edges by dst; also permute+convert edge_attr rows to bf16 in sorted order
__global__ __launch_bounds__(256) void k_scatter(const int* __restrict__ srcA, const int* __restrict__ dstA,
                                                 const float* __restrict__ ea,
                                                 const int* __restrict__ offs, int* __restrict__ cnt,
                                                 int* __restrict__ srcs2, int* __restrict__ dsts2,
                                                 short* __restrict__ ea2s){
    int e = blockIdx.x * 256 + threadIdx.x;
    if (e < EE){
        int d = dstA[e];
        int pos = offs[d] + atomicAdd(&cnt[d], 1);
        srcs2[pos] = srcA[e];
        dsts2[pos] = d;
        const float* r = ea + (size_t)e * 32;
        short* o = ea2s + (size_t)pos * 32;
        #pragma unroll
        for (int qd = 0; qd < 8; qd++){
            f32x4 v = *(const f32x4*)(r + qd * 4);
            short4v h = {bf16c(v[0]), bf16c(v[1]), bf16c(v[2]), bf16c(v[3])};
            *(short4v*)(o + qd * 4) = h;
        }
    }
}

__global__ __launch_bounds__(256) void k_fill(int* __restrict__ srcs2, int* __restrict__ dsts2){
    int i = blockIdx.x * 256 + threadIdx.x;
    if (i < NN){ srcs2[EE + i] = i; dsts2[EE + i] = i; }
}

// loop_attr rows (appended at ea2s[EE..TOT)): mean of incoming sorted rows, bf16.
__global__ __launch_bounds__(256) void k_loopattr(short* __restrict__ ea2s, const int* __restrict__ offs){
    int tid = blockIdx.x * 256 + threadIdx.x;
    if (tid >= NN * CC) return;
    int n = tid >> 5, c = tid & 31;
    int b = offs[n], e = offs[n + 1];
    float s = 0.f;
    for (int p = b; p < e; ++p) s += bf2f((unsigned short)ea2s[(size_t)p * 32 + c]);
    ea2s[(size_t)(EE + n) * 32 + c] = bf16c(s / fmaxf((float)(e - b), 1.0f));
}

// ---------------- weight prep ----------------
// wt: Wt[c][k] = bf16(W[k][c]) for the 8 DxD matrices (Wl0,Wl1,Wr0,Wr1,w10,w11,w20,w21)

__global__ __launch_bounds__(256) void k_prepw(const float* __restrict__ Wl, const float* __restrict__ Wr,
                                               const float* __restrict__ w1, const float* __restrict__ w2,
                                               short* __restrict__ wt){
    int gid = blockIdx.x * 256 + threadIdx.x;      // 8 * 16384
    int mi = gid >> 14;
    int flat = gid & 16383;
    const float* base = (mi < 2) ? Wl : (mi < 4) ? Wr : (mi < 6) ? w1 : w2;
    const float* src = base + (size_t)(mi & 1) * 16384;
    int k = flat >> 7, c = flat & 127;
    wt[(size_t)mi * 16384 + c * 128 + k] = bf16c(src[flat]);
}

// weA: k_score A-fragments, laid out so af[t] = 16B vector load per lane.
// weA[((l*8 + t)*64 + lane)*8 + j] = bf16(We[l][k=q*8+j][d=t*16+m]), q=lane>>4, m=lane&15

__global__ __launch_bounds__(256) void k_prepwe(const float* __restrict__ We, short* __restrict__ weA){
    int gid = blockIdx.x * 256 + threadIdx.x;      // LL*8*64*8 = 8192
    if (gid >= LL * 4096) return;
    int j = gid & 7;
    int lane = (gid >> 3) & 63;
    int t = (gid >> 9) & 7;
    int l = gid >> 12;
    int q = lane >> 4, m = lane & 15;
    weA[gid] = bf16c(We[(size_t)l * 4096 + (q * 8 + j) * 128 + t * 16 + m]);
}

// nodes fp32 -> bf16
__global__ __launch_bounds__(256) void k_prepx(const float* __restrict__ x, short* __restrict__ xb){
    int i = blockIdx.x * 256 + threadIdx.x;        // over NN*DD/4
    if (i >= NN * DD / 4) return;
    f32x4 v = *(const f32x4*)(x + (size_t)i * 4);
    short4v h = {bf16c(v[0]), bf16c(v[1]), bf16c(v[2]), bf16c(v[3])};
    *(short4v*)(xb + (size_t)i * 4) = h;
}

// ---------------- MFMA GEMM: C[r][c] = act( sum_k X[r][k] W[k][c] + bias[c] ) ----------------

__global__ __launch_bounds__(256) void k_mg(const short* __restrict__ Xb, const short* __restrict__ Wt,
                                            const float* __restrict__ bv, float* __restrict__ Yf,
                                            unsigned short* __restrict__ Yb, int act, int mode){
    int lane = threadIdx.x & 63;
    int wave = threadIdx.x >> 6;
    int q = lane >> 4;
    int m = lane & 15;
    int cw0 = wave * 32;
    int r0 = blockIdx.x * 64;

    short8 af[2][4];
    #pragma unroll
    for (int ct = 0; ct < 2; ct++)
        #pragma unroll
        for (int ks = 0; ks < 4; ks++)
            af[ct][ks] = *(const short8*)(Wt + (size_t)(cw0 + ct * 16 + m) * 128 + ks * 32 + q * 8);

    f32x4 bq[2];
    #pragma unroll
    for (int ct = 0; ct < 2; ct++)
        bq[ct] = *(const f32x4*)(bv + cw0 + ct * 16 + q * 4);

    #pragma unroll
    for (int rt = 0; rt < 4; rt++){
        int r = r0 + rt * 16 + m;
        int rc = (r < NN) ? r : NN - 1;
        short8 bf[4];
        #pragma unroll
        for (int ks = 0; ks < 4; ks++)
            bf[ks] = *(const short8*)(Xb + (size_t)rc * 128 + ks * 32 + q * 8);

        f32x4 ac0 = {0.f, 0.f, 0.f, 0.f};
        f32x4 ac1 = {0.f, 0.f, 0.f, 0.f};
        #pragma unroll
        for (int ks = 0; ks < 4; ks++){
            ac0 = __builtin_amdgcn_mfma_f32_16x16x32_bf16(af[0][ks], bf[ks], ac0, 0, 0, 0);
            ac1 = __builtin_amdgcn_mfma_f32_16x16x32_bf16(af[1][ks], bf[ks], ac1, 0, 0, 0);
        }
        int rr = r0 + rt * 16 + m;
        if (rr < NN){
            #pragma unroll
            for (int ct = 0; ct < 2; ct++){
                f32x4 a = ct ? ac1 : ac0;
                f32x4 v;
                #pragma unroll
                for (int j = 0; j < 4; j++){
                    float x = a[j] + bq[ct][j];
                    if (act) x = fmaxf(x, 0.f);
                    v[j] = x;
                }
                int c0 = cw0 + ct * 16 + q * 4;
                if (mode & 1)
                    *(f32x4*)(Yf + (size_t)rr * 128 + c0) = v;
                if (mode & 2){
                    short4v h = {bf16c(v[0]), bf16c(v[1]), bf16c(v[2]), bf16c(v[3])};
                    *(short4v*)(Yb + (size_t)rr * 128 + c0) = h;
                }
            }
        }
    }
}

// ---------------- fused edge-score kernel: 2 MFMA tiles per iteration ----------------
// alpha[pos][h] = sum_c att[h,c] * leaky(xl[src][c] + xr[dst][c] + (ea2s[pos]@We)[c])

__global__ __launch_bounds__(256) void k_score(const short* __restrict__ ea2s,
                                               const int* __restrict__ srcs2, const int* __restrict__ dsts2,
                                               const unsigned short* __restrict__ xlb,
                                               const unsigned short* __restrict__ xrb,
                                               const short* __restrict__ weA, const float* __restrict__ att,
                                               float* __restrict__ alpha){
    int lane = threadIdx.x & 63;
    int q = lane >> 4;
    int m = lane & 15;

    short8 af[8];
    #pragma unroll
    for (int t = 0; t < 8; t++)
        af[t] = *(const short8*)(weA + ((size_t)t * 64 + lane) * 8);

    int wid = (blockIdx.x * 256 + threadIdx.x) >> 6;
    int nw = (gridDim.x * 256) >> 6;
    for (int g = wid * 2; g < NG; g += nw * 2){
        int posA = g * 16 + m;
        bool hB = (g + 1) < NG;
        int posB = hB ? posA + 16 : posA;

        int sA = srcs2[posA], dA = dsts2[posA];
        int sB = srcs2[posB], dB = dsts2[posB];
        short8 bfA = *(const short8*)(ea2s + (size_t)posA * 32 + q * 8);
        short8 bfB = *(const short8*)(ea2s + (size_t)posB * 32 + q * 8);

        const unsigned short* xlA = xlb + (size_t)sA * 128 + q * 4;
        const unsigned short* xrA = xrb + (size_t)dA * 128 + q * 4;
        const unsigned short* xlB = xlb + (size_t)sB * 128 + q * 4;
        const unsigned short* xrB = xrb + (size_t)dB * 128 + q * 4;

        ushort4v xvA[8], rvA[8], xvB[8], rvB[8];
        #pragma unroll
        for (int t = 0; t < 8; t++){
            xvA[t] = *(const ushort4v*)(xlA + t * 16);
            rvA[t] = *(const ushort4v*)(xrA + t * 16);
            xvB[t] = *(const ushort4v*)(xlB + t * 16);
            rvB[t] = *(const ushort4v*)(xrB + t * 16);
        }

        float psA[4] = {0.f,0.f,0.f,0.f}, psB[4] = {0.f,0.f,0.f,0.f};
        #pragma unroll
        for (int t = 0; t < 8; t++){
            f32x4 z = {0.f,0.f,0.f,0.f};
            f32x4 cA = __builtin_amdgcn_mfma_f32_16x16x32_bf16(af[t], bfA, z, 0, 0, 0);
            f32x4 cB = __builtin_amdgcn_mfma_f32_16x16x32_bf16(af[t], bfB, z, 0, 0, 0);
            f32x4 av = *(const f32x4*)(att + t * 16 + q * 4);
            #pragma unroll
            for (int r = 0; r < 4; r++){
                float ma = cA[r] + bf2f(xvA[t][r]) + bf2f(rvA[t][r]);
                float mb = cB[r] + bf2f(xvB[t][r]) + bf2f(rvB[t][r]);
                ma = (ma > 0.f) ? ma : 0.2f * ma;
                mb = (mb > 0.f) ? mb : 0.2f * mb;
                psA[t >> 1] = fmaf(av[r], ma, psA[t >> 1]);
                psB[t >> 1] = fmaf(av[r], mb, psB[t >> 1]);
            }
        }
        #pragma unroll
        for (int h = 0; h < 4; h++){
            psA[h] += __shfl_xor(psA[h], 16);
            psA[h] += __shfl_xor(psA[h], 32);
            psB[h] += __shfl_xor(psB[h], 16);
            psB[h] += __shfl_xor(psB[h], 32);
        }
        if (lane < 16){
            f32x4 oA = {psA[0], psA[1], psA[2], psA[3]};
            *(f32x4*)(alpha + (size_t)posA * 4) = oA;
            if (hB){
                f32x4 oB = {psB[0], psB[1], psB[2], psB[3]};
                *(f32x4*)(alpha + (size_t)posB * 4) = oB;
            }
        }
    }
}

// ---------------- GATv2 softmax + aggregation (bf16 gathers, 2 adjacent ch/lane) ----------------
// lane owns channels {2*lane, 2*lane+1}; both in head h = lane>>4 -> single softmax state.

__global__ __launch_bounds__(256) void k_gat2(const unsigned short* __restrict__ xlb,
                                              const int* __restrict__ srcs2, const int* __restrict__ offs,
                                              const float* __restrict__ alpha, const float* __restrict__ bias,
                                              unsigned short* __restrict__ out){
    int n = blockIdx.x * 4 + (threadIdx.x >> 6);
    int lane = threadIdx.x & 63;
    int c0 = lane * 2;
    int h = lane >> 4;

    int beg = offs[n];
    int deg = offs[n + 1] - beg;
    int cnt = deg + 1;   // + self-loop (position EE+n)

    float M = -INFINITY, S = 0.f, A0 = 0.f, A1 = 0.f;

    for (int i = 0; i < cnt; i += 4){
        float a[4]; unsigned x[4];
        #pragma unroll
        for (int u = 0; u < 4; u++){
            int iu = i + u;
            int p = (iu < deg) ? beg + iu : EE + n;
            int s = srcs2[p];
            a[u] = alpha[(size_t)p * 4 + h];
            x[u] = *(const unsigned*)(xlb + (size_t)s * 128 + c0);
            if (iu >= cnt) a[u] = -INFINITY;
        }
        float nM = fmaxf(fmaxf(fmaxf(a[0], a[1]), fmaxf(a[2], a[3])), M);
        float rs = __expf(M - nM);
        float w0 = __expf(a[0] - nM);
        float w1 = __expf(a[1] - nM);
        float w2 = __expf(a[2] - nM);
        float w3 = __expf(a[3] - nM);
        S = S * rs + w0 + w1 + w2 + w3;
        A0 = A0 * rs + w0 * bf2f((unsigned short)(x[0] & 0xffffu))
                     + w1 * bf2f((unsigned short)(x[1] & 0xffffu))
                     + w2 * bf2f((unsigned short)(x[2] & 0xffffu))
                     + w3 * bf2f((unsigned short)(x[3] & 0xffffu));
        A1 = A1 * rs + w0 * bf2f((unsigned short)(x[0] >> 16))
                     + w1 * bf2f((unsigned short)(x[1] >> 16))
                     + w2 * bf2f((unsigned short)(x[2] >> 16))
                     + w3 * bf2f((unsigned short)(x[3] >> 16));
        M = nM;
    }
    float inv = 1.f / (S + 1e-16f);
    float v0 = A0 * inv + bias[c0];
    float v1 = A1 * inv + bias[c0 + 1];
    unsigned o = ((unsigned)(unsigned short)bf16c(v0)) | (((unsigned)(unsigned short)bf16c(v1)) << 16);
    *(unsigned*)(out + (size_t)n * 128 + c0) = o;
}

// ---------------- driver ----------------

extern "C" void kernel_launch(void* const* d_in, const int* in_sizes, int n_in,
                              void* d_out, int out_size, void* d_ws, size_t ws_size,
                              hipStream_t stream){
    const float* nodes = (const float*)d_in[0];
    const int*   ei    = (const int*)d_in[1];
    const float* ea    = (const float*)d_in[2];
    const float* Wl    = (const float*)d_in[3];
    const float* bl    = (const float*)d_in[4];
    const float* Wr    = (const float*)d_in[5];
    const float* br    = (const float*)d_in[6];
    const float* We    = (const float*)d_in[7];
    const float* att   = (const float*)d_in[8];
    const float* bias  = (const float*)d_in[9];
    const float* w1    = (const float*)d_in[10];
    const float* b1    = (const float*)d_in[11];
    const float* w2    = (const float*)d_in[12];
    const float* b2    = (const float*)d_in[13];
    const int* srcA = ei;
    const int* dstA = ei + EE;

    char* ws = (char*)d_ws;
    size_t off = 0;
    auto alloc = [&](size_t bytes) -> char* {
        off = (off + 255) & ~(size_t)255;
        char* p = ws + off;
        off += bytes;
        return p;
    };
    int*   deg   = (int*)alloc(NN * 4);
    int*   cnt   = (int*)alloc(NN * 4);
    int*   offs  = (int*)alloc((NN + 1) * 4);
    int*   bsum  = (int*)alloc(64 * 4);
    int*   srcs2 = (int*)alloc((size_t)TOT * 4);
    int*   dsts2 = (int*)alloc((size_t)TOT * 4);
    short* ea2s  = (short*)alloc((size_t)TOT * CC * 2);
    float* alpha = (float*)alloc((size_t)TOT * 4 * 4);
    short* wt    = (short*)alloc((size_t)8 * 16384 * 2);          // 8 transposed bf16 weights
    short* weA   = (short*)alloc((size_t)LL * 4096 * 2);          // k_score A-frag table
    short* xb    = (short*)alloc((size_t)NN * DD * 2);            // current x, bf16
    unsigned short* xlb = (unsigned short*)alloc((size_t)NN * DD * 2);
    unsigned short* xrb = (unsigned short*)alloc((size_t)NN * DD * 2);
    unsigned short* bgb = (unsigned short*)alloc((size_t)NN * DD * 2);  // gat2 out, bf16
    unsigned short* bhb = (unsigned short*)alloc((size_t)NN * DD * 2);  // MLP hidden, bf16
    unsigned short* bxb = (unsigned short*)alloc((size_t)NN * DD * 2);  // inter-layer x, bf16

    hipMemsetAsync(deg, 0, NN * 4, stream);
    hipMemsetAsync(cnt, 0, NN * 4, stream);
    k_hist<<<(EE + 255) / 256, 256, 0, stream>>>(dstA, deg);
    int nb = (NN + 1023) / 1024;
    k_scan1<<<nb, 1024, 0, stream>>>(deg, offs, bsum);
    k_scan2<<<1, 64, 0, stream>>>(bsum, nb);
    k_scan3<<<nb, 1024, 0, stream>>>(offs, bsum);
    k_scatter<<<(EE + 255) / 256, 256, 0, stream>>>(srcA, dstA, ea, offs, cnt, srcs2, dsts2, ea2s);
    k_fill<<<(NN + 255) / 256, 256, 0, stream>>>(srcs2, dsts2);
    k_loopattr<<<(NN * CC + 255) / 256, 256, 0, stream>>>(ea2s, offs);
    k_prepw<<<8 * 16384 / 256, 256, 0, stream>>>(Wl, Wr, w1, w2, wt);
    k_prepwe<<<(LL * 4096 + 255) / 256, 256, 0, stream>>>(We, weA);
    k_prepx<<<(NN * DD / 4 + 255) / 256, 256, 0, stream>>>(nodes, xb);

    const int GB = (NN + 63) / 64;   // 782
    short* wtWl = wt;
    short* wtWr = wt + 2 * 16384;
    short* wtw1 = wt + 4 * 16384;
    short* wtw2 = wt + 6 * 16384;

    const short* x = xb;
    for (int l = 0; l < LL; l++){
        k_mg<<<GB, 256, 0, stream>>>(x, wtWl + l * 16384, bl + l * DD, nullptr, xlb, 0, 2);
        k_mg<<<GB, 256, 0, stream>>>(x, wtWr + l * 16384, br + l * DD, nullptr, xrb, 0, 2);
        k_score<<<4096, 256, 0, stream>>>(ea2s, srcs2, dsts2, xlb, xrb,
                                          weA + l * 4096, att + l * HH * CC, alpha);
        k_gat2<<<NN / 4, 256, 0, stream>>>(xlb, srcs2, offs, alpha, bias + l * DD, bgb);
        k_mg<<<GB, 256, 0, stream>>>((const short*)bgb, wtw1 + l * 16384, b1 + l * DD, nullptr, bhb, 1, 2);
        if (l == LL - 1)
            k_mg<<<GB, 256, 0, stream>>>((const short*)bhb, wtw2 + l * 16384, b2 + l * DD,
                                         (float*)d_out, nullptr, 0, 1);
        else
            k_mg<<<GB, 256, 0, stream>>>((const short*)bhb, wtw2 + l * 16384, b2 + l * DD,
                                         nullptr, bxb, 0, 2);
        x = (const short*)bxb;
    }
}